// Round 9
// baseline (674.297 us; speedup 1.0000x reference)
//
#include <hip/hip_runtime.h>
#include <hip/hip_bf16.h>

typedef __hip_bfloat16 bf16;
typedef __attribute__((ext_vector_type(8))) short short8;
typedef __attribute__((ext_vector_type(4))) short s16x4;
typedef __attribute__((ext_vector_type(4))) float f32x4;

#define CDIM 512
#define BDIM 4
#define HDIM 8
#define HDQ  64
#define NQ   1024
#define NKV  2048
#define LAYERS 4
#define SPLIT 2

#if defined(__has_builtin)
#if __has_builtin(__builtin_amdgcn_global_load_lds)
#define USE_GLL 1
#endif
#endif

static __device__ __forceinline__ short f2s(float f) {
    bf16 h = __float2bfloat16(f);
    return *reinterpret_cast<short*>(&h);
}

// ---------------- elementwise / small kernels ----------------

__global__ __launch_bounds__(256) void convall_k(
    const float* __restrict__ s0, const float* __restrict__ s1,
    const float* __restrict__ s2, const float* __restrict__ s3,
    const float* __restrict__ s4,
    bf16* __restrict__ d0, bf16* __restrict__ d1, bf16* __restrict__ d2,
    bf16* __restrict__ d3, bf16* __restrict__ d4) {
    int gid = blockIdx.x * 256 + threadIdx.x;   // 2,621,440 total (x4 elems)
    const float* src; bf16* dst; int off;
    if (gid < 1048576)      { src = s0; dst = d0; off = gid; }
    else if (gid < 1835008) { src = s1; dst = d1; off = gid - 1048576; }
    else if (gid < 2097152) { src = s2; dst = d2; off = gid - 1835008; }
    else if (gid < 2359296) { src = s3; dst = d3; off = gid - 2097152; }
    else                    { src = s4; dst = d4; off = gid - 2359296; }
    f32x4 v = *(const f32x4*)(src + (size_t)off * 4);
    s16x4 o;
    o[0] = f2s(v[0]); o[1] = f2s(v[1]); o[2] = f2s(v[2]); o[3] = f2s(v[3]);
    *(s16x4*)(dst + (size_t)off * 4) = o;
}

// one wave per output row-dot (32768 waves); silu fused on the t-loads.
__global__ __launch_bounds__(256) void modall_k(const float* __restrict__ diff_ts,
    const float* __restrict__ aw_attn, const float* __restrict__ ab_attn,
    const float* __restrict__ aw_ffn,  const float* __restrict__ ab_ffn,
    float* __restrict__ mod) {
    int wv = blockIdx.x * 4 + (threadIdx.x >> 6);   // 32768 total
    int lane = threadIdx.x & 63;
    int col  = wv & 1023;
    int b    = (wv >> 10) & 3;
    int kind = (wv >> 12) & 1;
    int l    = wv >> 13;
    const float* w = (kind ? aw_ffn : aw_attn) + ((size_t)l * 1024 + col) * CDIM + lane * 8;
    const float* tb = diff_ts + b * CDIM + lane * 8;
    f32x4 w0 = *(const f32x4*)w;
    f32x4 w1 = *(const f32x4*)(w + 4);
    f32x4 t0 = *(const f32x4*)tb;
    f32x4 t1 = *(const f32x4*)(tb + 4);
    #pragma unroll
    for (int j = 0; j < 4; ++j) {
        t0[j] = t0[j] / (1.f + __expf(-t0[j]));
        t1[j] = t1[j] / (1.f + __expf(-t1[j]));
    }
    f32x4 pp = w0 * t0 + w1 * t1;
    float acc = (pp[0] + pp[1]) + (pp[2] + pp[3]);
    #pragma unroll
    for (int off = 32; off; off >>= 1) acc += __shfl_xor(acc, off);
    if (lane == 0)
        mod[wv] = acc + (kind ? ab_ffn : ab_attn)[l * 1024 + col];
}

// plain adaln (used once, for layer 0's aq from query)
__global__ __launch_bounds__(256) void adaln_k(const float* __restrict__ x,
                                               const float* __restrict__ mod,
                                               bf16* __restrict__ outb) {
    int i = blockIdx.x * 256 + threadIdx.x;  // 4096*512 total
    int c = i & 511;
    int b = (i >> 9) & 3;
    outb[i] = __float2bfloat16(x[i] * (1.f + mod[b * 1024 + c]) + mod[b * 1024 + 512 + c]);
}

// fused LayerNorm(x+res) [+ optional AdaLN of the LN output]
__global__ __launch_bounds__(256) void ln_ad_k(const float* __restrict__ x,
                                               const float* __restrict__ res,
                                               const float* __restrict__ g,
                                               const float* __restrict__ bb,
                                               const float* __restrict__ mod,
                                               float* __restrict__ ln_f,
                                               float* __restrict__ ln_f2,
                                               float* __restrict__ ad_f,
                                               bf16* __restrict__ ad_b) {
    int row = blockIdx.x;
    int t = threadIdx.x;
    size_t base = (size_t)row * CDIM;
    float v0 = x[base + t] + res[base + t];
    float v1 = x[base + t + 256] + res[base + t + 256];
    float s1 = v0 + v1;
    float s2 = v0 * v0 + v1 * v1;
    #pragma unroll
    for (int off = 32; off; off >>= 1) {
        s1 += __shfl_xor(s1, off);
        s2 += __shfl_xor(s2, off);
    }
    __shared__ float a1[4], a2[4];
    int w = t >> 6;
    if ((t & 63) == 0) { a1[w] = s1; a2[w] = s2; }
    __syncthreads();
    s1 = a1[0] + a1[1] + a1[2] + a1[3];
    s2 = a2[0] + a2[1] + a2[2] + a2[3];
    float mean = s1 * (1.f / 512.f);
    float var = s2 * (1.f / 512.f) - mean * mean;
    float rs = rsqrtf(var + 1e-5f);
    float y0 = (v0 - mean) * rs * g[t] + bb[t];
    float y1 = (v1 - mean) * rs * g[t + 256] + bb[t + 256];
    if (ln_f)  { ln_f[base + t] = y0;  ln_f[base + t + 256] = y1; }
    if (ln_f2) { ln_f2[base + t] = y0; ln_f2[base + t + 256] = y1; }
    if (mod) {
        int b = row & 3;
        float o0 = y0 * (1.f + mod[b * 1024 + t]) + mod[b * 1024 + 512 + t];
        float o1 = y1 * (1.f + mod[b * 1024 + t + 256]) + mod[b * 1024 + 512 + t + 256];
        if (ad_f) { ad_f[base + t] = o0; ad_f[base + t + 256] = o1; }
        ad_b[base + t] = __float2bfloat16(o0);
        ad_b[base + t + 256] = __float2bfloat16(o1);
    }
}

// ---------------- MFMA GEMM, 8-wave 128x64 tile ----------------
// out = A[MxK](bf16) * W[NxK](bf16)^T + bias. A-slab of 128 rows staged once
// for 8 waves (4x2 wave grid); BK=64 double-buffered; 2-way LDS chunk swizzle;
// XCD-chunked work remap (8 n-tiles sharing an A-panel -> one XCD).
// EPI 0: (+bias[n]) -> f32
// EPI 1: relu(+bias[n]) -> bf16
// EPI 2: (+bias[n])*scl, rotary(pos) -> bf16 head layout (b,h,nseq,hd)
template <int EPI, bool SWZ>
__global__ __launch_bounds__(512) void mgemm8_k(
    const bf16* __restrict__ A, const bf16* __restrict__ Wt,
    const float* __restrict__ bias, void* __restrict__ out0v,
    int M, int N, int K,
    const float* __restrict__ pos, float scl, int Nseq) {
    __shared__ bf16 As[2][2][128 * 32];   // 32 KB
    __shared__ bf16 Bs[2][2][64 * 32];    // 16 KB
    int t = threadIdx.x;
    int w = t >> 6;
    int lane = t & 63;
    int l16 = lane & 15;
    int quad = lane >> 4;
    int wy = w >> 1, wx = w & 1;   // 4x2 wave grid

    int flat = blockIdx.x;
    int nwg = gridDim.x;           // multiple of 8
    int s = SWZ ? ((flat & 7) * (nwg >> 3) + (flat >> 3)) : flat;
    int bn = (s & 7) * 64;         // n tile
    int bm = (s >> 3) * 128;       // m tile

    int lr2 = lane >> 2;                         // staging row 0..15
    int lc4 = (lane & 3) ^ ((lane >> 3) & 3);    // pre-swizzled source chunk

    f32x4 acc[2][2] = {};

    auto stage = [&](int buf, int k0) {
#if USE_GLL
        // A: each wave stages rows w*16..w*16+15 of the 128-row slab
        const bf16* sa = A + (size_t)(bm + w * 16 + lr2) * K + k0 + lc4 * 8;
        #pragma unroll
        for (int j = 0; j < 2; ++j) {
            __builtin_amdgcn_global_load_lds(
                (const unsigned int __attribute__((address_space(1)))*)(sa + j * 32),
                (unsigned int __attribute__((address_space(3)))*)(&As[buf][j][w * 512]),
                16, 0, 0);
        }
        // B: waves 0-3 stage the 64-row W tile
        if (w < 4) {
            const bf16* sb = Wt + (size_t)(bn + w * 16 + lr2) * K + k0 + lc4 * 8;
            #pragma unroll
            for (int j = 0; j < 2; ++j) {
                __builtin_amdgcn_global_load_lds(
                    (const unsigned int __attribute__((address_space(1)))*)(sb + j * 32),
                    (unsigned int __attribute__((address_space(3)))*)(&Bs[buf][j][w * 512]),
                    16, 0, 0);
            }
        }
#else
        for (int u = t; u < 1024; u += 512) {   // A: 2 ksub x 128 rows x 4 chunks
            int sub = u >> 9, c = u & 511;
            int row = c >> 2, c4 = c & 3;
            int srcc = c4 ^ ((row >> 1) & 3);
            *(uint4*)&As[buf][sub][row * 32 + c4 * 8] =
                *(const uint4*)(A + (size_t)(bm + row) * K + k0 + sub * 32 + srcc * 8);
        }
        {
            int u = t;                          // B: 512 units
            int sub = u >> 8, c = u & 255;
            int row = c >> 2, c4 = c & 3;
            int srcc = c4 ^ ((row >> 1) & 3);
            *(uint4*)&Bs[buf][sub][row * 32 + c4 * 8] =
                *(const uint4*)(Wt + (size_t)(bn + row) * K + k0 + sub * 32 + srcc * 8);
        }
#endif
    };

    stage(0, 0);
    __syncthreads();   // drains vmcnt(0): tile 0 resident
    int cur = 0;
    int rchunk = (quad ^ ((l16 >> 1) & 3)) * 8;   // swizzled read col (elements)

    for (int k0 = 0; k0 < K; k0 += 64) {
        if (k0 + 64 < K) stage(cur ^ 1, k0 + 64);  // prefetch overlaps compute

        #pragma unroll
        for (int kk = 0; kk < 2; ++kk) {
            short8 af[2], bfr[2];
            #pragma unroll
            for (int mt = 0; mt < 2; ++mt)
                af[mt] = *(const short8*)
                    &As[cur][kk][(wy * 32 + mt * 16 + l16) * 32 + rchunk];
            #pragma unroll
            for (int nt = 0; nt < 2; ++nt)
                bfr[nt] = *(const short8*)
                    &Bs[cur][kk][((wx * 2 + nt) * 16 + l16) * 32 + rchunk];
            #pragma unroll
            for (int mt = 0; mt < 2; ++mt)
                #pragma unroll
                for (int nt = 0; nt < 2; ++nt)
                    acc[mt][nt] = __builtin_amdgcn_mfma_f32_16x16x32_bf16(
                        af[mt], bfr[nt], acc[mt][nt], 0, 0, 0);
        }

        __syncthreads();   // prefetch landed, reads done
        cur ^= 1;
    }

    #pragma unroll
    for (int nt = 0; nt < 2; ++nt) {
        int n = bn + (wx * 2 + nt) * 16 + l16;
        float bnv = bias[n];
        #pragma unroll
        for (int mt = 0; mt < 2; ++mt) {
            #pragma unroll
            for (int r = 0; r < 4; ++r) {
                int m = bm + wy * 32 + mt * 16 + quad * 4 + r;
                float v = acc[mt][nt][r] + bnv;
                if (EPI == 0) {
                    ((float*)out0v)[(size_t)m * N + n] = v;
                } else if (EPI == 1) {
                    ((bf16*)out0v)[(size_t)m * N + n] = __float2bfloat16(fmaxf(v, 0.f));
                } else {  // EPI 2: rotary -> head layout
                    v *= scl;
                    int c = n;
                    int nseq = m >> 2, b = m & 3;
                    float part = __shfl_xor(v, 1);
                    const float* pp = pos + (((size_t)b * Nseq + nseq) * CDIM + c) * 2;
                    float cs = pp[0], sn = pp[1];
                    float o = (l16 & 1) ? (v * cs + part * sn) : (v * cs - part * sn);
                    bf16* op = (bf16*)out0v +
                               ((size_t)(b * HDIM + (c >> 6)) * Nseq + nseq) * HDQ + (c & 63);
                    *op = __float2bfloat16(o);
                }
            }
        }
    }
}

// ---------------- fused K + V^T projection, 8-wave 128x64 tile ----------------
// A = val_bf rows bm..bm+127 staged once for 8 waves; Bk/Bv 64-channel tiles.
__global__ __launch_bounds__(512) void kv8_k(
    const bf16* __restrict__ val, const bf16* __restrict__ Wk,
    const bf16* __restrict__ Wv, const float* __restrict__ biask,
    const float* __restrict__ biasv, bf16* __restrict__ kh,
    bf16* __restrict__ vt, const float* __restrict__ vpos) {
    __shared__ bf16 As[2][2][128 * 32];   // 32 KB
    __shared__ bf16 Bk[2][2][64 * 32];    // 16 KB
    __shared__ bf16 Bv[2][2][64 * 32];    // 16 KB
    int t = threadIdx.x;
    int w = t >> 6;
    int lane = t & 63;
    int l16 = lane & 15;
    int quad = lane >> 4;
    int wy = w >> 1, wx = w & 1;   // 4x2 wave grid

    // XCD-chunked: 512 blocks -> 64-block chunks; 8 consecutive s share bm
    int flat = blockIdx.x;
    int s = (flat & 7) * 64 + (flat >> 3);
    int bn = (s & 7) * 64;        // channel tile
    int bm = (s >> 3) * 128;      // val-row tile
    const int K = CDIM;

    int lr2 = lane >> 2;
    int lc4 = (lane & 3) ^ ((lane >> 3) & 3);

    f32x4 acck[2][2] = {};
    f32x4 accv[2][2] = {};

    auto stage = [&](int buf, int k0) {
#if USE_GLL
        const bf16* sa = val + (size_t)(bm + w * 16 + lr2) * K + k0 + lc4 * 8;
        #pragma unroll
        for (int j = 0; j < 2; ++j) {
            __builtin_amdgcn_global_load_lds(
                (const unsigned int __attribute__((address_space(1)))*)(sa + j * 32),
                (unsigned int __attribute__((address_space(3)))*)(&As[buf][j][w * 512]),
                16, 0, 0);
        }
        if (w < 4) {
            const bf16* sk = Wk + (size_t)(bn + w * 16 + lr2) * K + k0 + lc4 * 8;
            #pragma unroll
            for (int j = 0; j < 2; ++j) {
                __builtin_amdgcn_global_load_lds(
                    (const unsigned int __attribute__((address_space(1)))*)(sk + j * 32),
                    (unsigned int __attribute__((address_space(3)))*)(&Bk[buf][j][w * 512]),
                    16, 0, 0);
            }
        } else {
            const bf16* sv = Wv + (size_t)(bn + (w - 4) * 16 + lr2) * K + k0 + lc4 * 8;
            #pragma unroll
            for (int j = 0; j < 2; ++j) {
                __builtin_amdgcn_global_load_lds(
                    (const unsigned int __attribute__((address_space(1)))*)(sv + j * 32),
                    (unsigned int __attribute__((address_space(3)))*)(&Bv[buf][j][(w - 4) * 512]),
                    16, 0, 0);
            }
        }
#else
        for (int u = t; u < 1024; u += 512) {   // A: 2 ksub x 128 rows x 4 chunks
            int sub = u >> 9, c = u & 511;
            int row = c >> 2, c4 = c & 3;
            int srcc = c4 ^ ((row >> 1) & 3);
            *(uint4*)&As[buf][sub][row * 32 + c4 * 8] =
                *(const uint4*)(val + (size_t)(bm + row) * K + k0 + sub * 32 + srcc * 8);
        }
        {
            int u = t;                          // Bk/Bv: 512 units each
            int sub = u >> 8, c = u & 255;
            int row = c >> 2, c4 = c & 3;
            int srcc = c4 ^ ((row >> 1) & 3);
            *(uint4*)&Bk[buf][sub][row * 32 + c4 * 8] =
                *(const uint4*)(Wk + (size_t)(bn + row) * K + k0 + sub * 32 + srcc * 8);
            *(uint4*)&Bv[buf][sub][row * 32 + c4 * 8] =
                *(const uint4*)(Wv + (size_t)(bn + row) * K + k0 + sub * 32 + srcc * 8);
        }
#endif
    };

    stage(0, 0);
    __syncthreads();
    int cur = 0;
    int rchunk = (quad ^ ((l16 >> 1) & 3)) * 8;

    for (int k0 = 0; k0 < K; k0 += 64) {
        if (k0 + 64 < K) stage(cur ^ 1, k0 + 64);

        #pragma unroll
        for (int kk = 0; kk < 2; ++kk) {
            short8 af[2], bkf[2], bvf[2];
            #pragma unroll
            for (int mt = 0; mt < 2; ++mt)
                af[mt] = *(const short8*)
                    &As[cur][kk][(wy * 32 + mt * 16 + l16) * 32 + rchunk];
            #pragma unroll
            for (int nt = 0; nt < 2; ++nt) {
                bkf[nt] = *(const short8*)
                    &Bk[cur][kk][((wx * 2 + nt) * 16 + l16) * 32 + rchunk];
                bvf[nt] = *(const short8*)
                    &Bv[cur][kk][((wx * 2 + nt) * 16 + l16) * 32 + rchunk];
            }
            #pragma unroll
            for (int mt = 0; mt < 2; ++mt)
                #pragma unroll
                for (int nt = 0; nt < 2; ++nt) {
                    acck[mt][nt] = __builtin_amdgcn_mfma_f32_16x16x32_bf16(
                        af[mt], bkf[nt], acck[mt][nt], 0, 0, 0);
                    accv[mt][nt] = __builtin_amdgcn_mfma_f32_16x16x32_bf16(
                        af[mt], bvf[nt], accv[mt][nt], 0, 0, 0);
                }
        }

        __syncthreads();
        cur ^= 1;
    }

    #pragma unroll
    for (int nt = 0; nt < 2; ++nt) {
        int n = bn + (wx * 2 + nt) * 16 + l16;
        float bk_n = biask[n];
        float bv_n = biasv[n];
        int d = n & 63, hh = n >> 6;
        #pragma unroll
        for (int mt = 0; mt < 2; ++mt) {
            #pragma unroll
            for (int r = 0; r < 4; ++r) {
                int m = bm + wy * 32 + mt * 16 + quad * 4 + r;
                int nseq = m >> 2, b = m & 3;
                // K path: rotary -> head layout
                float v = acck[mt][nt][r] + bk_n;
                float part = __shfl_xor(v, 1);
                const float* pp = vpos + (((size_t)b * NKV + nseq) * CDIM + n) * 2;
                float cs = pp[0], sn = pp[1];
                float o = (l16 & 1) ? (v * cs + part * sn) : (v * cs - part * sn);
                kh[((size_t)(b * HDIM + hh) * NKV + nseq) * HDQ + d] =
                    __float2bfloat16(o);
                // V path: scatter transpose -> vt[bh][d][key]
                float vv = accv[mt][nt][r] + bv_n;
                vt[((size_t)(b * HDIM + hh) * HDQ + d) * NKV + nseq] =
                    __float2bfloat16(vv);
            }
        }
    }
}

// ---------------- MFMA flash attention v8: 8-wave blocks ----------------
__global__ __launch_bounds__(512) void attn8_k(const bf16* __restrict__ qh,
                                               const bf16* __restrict__ kh,
                                               const bf16* __restrict__ vT,
                                               float* __restrict__ pl,
                                               float* __restrict__ pacc) {
    __shared__ short Kb[2][64 * 64];   // [key][d], chunk-swizzled
    __shared__ short Vb[2][64 * 64];   // [d][key], chunk-swizzled
    __shared__ short Ps[8][16 * 64];   // per-wave P, chunk-swizzled
    int t = threadIdx.x;
    int wave = t >> 6, lane = t & 63;
    int l16 = lane & 15, quad = lane >> 4;

    // XCD swizzle: 512 blocks, 8 XCDs -> 64-block chunks. grp = bh*2+split.
    int b0 = blockIdx.x;
    int newid = (b0 & 7) * 64 + (b0 >> 3);
    int qtile = newid & 7;             // 8 q-tiles of 128 rows
    int grp = newid >> 3;
    int split = grp & 1;
    int bh = grp >> 1;
    int q0 = qtile * 128 + wave * 16;
    int kbase = split * (NKV / SPLIT);

    const bf16* qbase = qh + ((size_t)bh * NQ + q0) * HDQ;
    short8 aq0 = *(const short8*)(qbase + (size_t)l16 * HDQ + quad * 8);
    short8 aq1 = *(const short8*)(qbase + (size_t)l16 * HDQ + 32 + quad * 8);
    const bf16* kbh = kh + ((size_t)bh * NKV + kbase) * HDQ;
    const bf16* vbh = vT + (size_t)bh * HDQ * NKV + kbase;

    int r0 = wave * 8;             // this wave stages rows r0..r0+7 of K and V^T
    int lr = lane >> 3;            // row within the 8-row gll granule
    int swz_src = ((lane & 7) ^ lr) * 8;  // pre-swizzled source chunk (elements)

    auto stage = [&](int buf, int kt) {
#if USE_GLL
        __builtin_amdgcn_global_load_lds(
            (const unsigned int __attribute__((address_space(1)))*)
                (kbh + (size_t)(kt + r0 + lr) * HDQ + swz_src),
            (unsigned int __attribute__((address_space(3)))*)&Kb[buf][r0 * 64],
            16, 0, 0);
        __builtin_amdgcn_global_load_lds(
            (const unsigned int __attribute__((address_space(1)))*)
                (vbh + (size_t)(r0 + lr) * NKV + kt + swz_src),
            (unsigned int __attribute__((address_space(3)))*)&Vb[buf][r0 * 64],
            16, 0, 0);
#else
        int rr = r0 + lr;
        int lc = lane & 7;
        *(short8*)&Kb[buf][rr * 64 + ((lc ^ (rr & 7)) * 8)] =
            *(const short8*)(kbh + (size_t)(kt + rr) * HDQ + lc * 8);
        *(short8*)&Vb[buf][rr * 64 + ((lc ^ (rr & 7)) * 8)] =
            *(const short8*)(vbh + (size_t)rr * NKV + kt + lc * 8);
#endif
    };

    f32x4 accO[4] = {};
    float lsum[4] = {0.f, 0.f, 0.f, 0.f};

    stage(0, 0);
    __syncthreads();   // vmcnt(0) drain: tile 0 resident
    int cur = 0;
    int swz_m = l16 & 7;

    for (int kt = 0; kt < NKV / SPLIT; kt += 64) {
        if (kt + 64 < NKV / SPLIT) stage(cur ^ 1, kt + 64);  // prefetch

        // QK^T: S[16q x 64k]
        f32x4 sc[4] = {};
        #pragma unroll
        for (int nt = 0; nt < 4; ++nt) {
            const short* kr = &Kb[cur][(nt * 16 + l16) * 64];
            short8 bk0 = *(const short8*)&kr[(quad ^ swz_m) * 8];
            short8 bk1 = *(const short8*)&kr[((quad + 4) ^ swz_m) * 8];
            sc[nt] = __builtin_amdgcn_mfma_f32_16x16x32_bf16(aq0, bk0, sc[nt], 0, 0, 0);
            sc[nt] = __builtin_amdgcn_mfma_f32_16x16x32_bf16(aq1, bk1, sc[nt], 0, 0, 0);
        }

        // softmax numerators (no max; scores are O(1) by construction).
        // q already carries log2e, so exp2f directly.
        #pragma unroll
        for (int r = 0; r < 4; ++r) {
            float p0 = exp2f(sc[0][r]);
            float p1 = exp2f(sc[1][r]);
            float p2 = exp2f(sc[2][r]);
            float p3 = exp2f(sc[3][r]);
            lsum[r] += (p0 + p1) + (p2 + p3);
            int pr = quad * 4 + r;
            short* prow = &Ps[wave][pr * 64];
            int pm = pr & 7;
            int ch = l16 >> 3, kl = l16 & 7;
            prow[((ch ^ pm) << 3) + kl]       = f2s(p0);  // key l16       (chunk ch)
            prow[(((ch + 2) ^ pm) << 3) + kl] = f2s(p1);  // key 16+l16
            prow[(((ch + 4) ^ pm) << 3) + kl] = f2s(p2);  // key 32+l16
            prow[(((ch + 6) ^ pm) << 3) + kl] = f2s(p3);  // key 48+l16
        }

        // PV: O[16q x 64d] += P[16x64] * V[64x64]
        const short* prd = &Ps[wave][l16 * 64];
        short8 pa0 = *(const short8*)&prd[(quad ^ swz_m) * 8];
        short8 pa1 = *(const short8*)&prd[((quad + 4) ^ swz_m) * 8];
        #pragma unroll
        for (int nt = 0; nt < 4; ++nt) {
            const short* vr = &Vb[cur][(nt * 16 + l16) * 64];
            short8 bv0 = *(const short8*)&vr[(quad ^ swz_m) * 8];
            short8 bv1 = *(const short8*)&vr[((quad + 4) ^ swz_m) * 8];
            accO[nt] = __builtin_amdgcn_mfma_f32_16x16x32_bf16(pa0, bv0, accO[nt], 0, 0, 0);
            accO[nt] = __builtin_amdgcn_mfma_f32_16x16x32_bf16(pa1, bv1, accO[nt], 0, 0, 0);
        }

        __syncthreads();   // single barrier per tile; drains prefetch vmcnt
        cur ^= 1;
    }

    #pragma unroll
    for (int r = 0; r < 4; ++r) {
        #pragma unroll
        for (int off = 1; off < 16; off <<= 1) lsum[r] += __shfl_xor(lsum[r], off);
    }

    size_t rowbase = ((size_t)split * 32 + bh) * NQ + q0;
    #pragma unroll
    for (int r = 0; r < 4; ++r) {
        size_t row = rowbase + quad * 4 + r;
        if (l16 == 0) pl[row] = lsum[r];
        #pragma unroll
        for (int nt = 0; nt < 4; ++nt)
            pacc[row * 64 + nt * 16 + l16] = accO[nt][r];
    }
}

// combine SPLIT partials -> bf16 attn output in (q, b, c) layout, x4 vectorized
__global__ __launch_bounds__(256) void attn_comb_k(const float* __restrict__ pl,
                                                   const float* __restrict__ pacc,
                                                   bf16* __restrict__ o) {
    int idx = blockIdx.x * 256 + threadIdx.x;   // 512K total (x4 elems)
    int d4 = (idx & 15) << 2;
    int row = idx >> 4;            // bh*NQ + q
    int q = row & (NQ - 1);
    int bh = row >> 10;
    const int S = 32 * NQ;
    float rl = 1.0f / (pl[row] + pl[S + row]);
    f32x4 a = *(const f32x4*)&pacc[(size_t)row * 64 + d4];
    f32x4 b = *(const f32x4*)&pacc[(size_t)(S + row) * 64 + d4];
    int bsel = bh >> 3, h = bh & 7;
    s16x4 o4;
    #pragma unroll
    for (int j = 0; j < 4; ++j) o4[j] = f2s((a[j] + b[j]) * rl);
    *(s16x4*)&o[((size_t)(q * BDIM + bsel)) * CDIM + h * HDQ + d4] = o4;
}

// ---------------- host side ----------------

extern "C" void kernel_launch(void* const* d_in, const int* in_sizes, int n_in,
                              void* d_out, int out_size, void* d_ws, size_t ws_size,
                              hipStream_t stream) {
    const float* query     = (const float*)d_in[0];
    const float* value     = (const float*)d_in[1];
    const float* diff_ts   = (const float*)d_in[2];
    const float* query_pos = (const float*)d_in[3];
    const float* value_pos = (const float*)d_in[4];
    const float* aw_attn   = (const float*)d_in[5];
    const float* ab_attn   = (const float*)d_in[6];
    const float* in_w      = (const float*)d_in[7];
    const float* in_b      = (const float*)d_in[8];
    const float* out_w     = (const float*)d_in[9];
    const float* out_b     = (const float*)d_in[10];
    const float* ln1_g     = (const float*)d_in[11];
    const float* ln1_b     = (const float*)d_in[12];
    const float* aw_ffn    = (const float*)d_in[13];
    const float* ab_ffn    = (const float*)d_in[14];
    const float* w1        = (const float*)d_in[15];
    const float* b1        = (const float*)d_in[16];
    const float* w2        = (const float*)d_in[17];
    const float* b2        = (const float*)d_in[18];
    const float* ln2_g     = (const float*)d_in[19];
    const float* ln2_b     = (const float*)d_in[20];
    float* out_f = (float*)d_out;

    float* ws      = (float*)d_ws;
    float* mod_ws  = ws + 2048;                 // 32768
    float* q_cur   = ws + 34816;                // 2,097,152
    float* buf_a   = q_cur + 2097152;           // 2,097,152 (xa f32 for LN2)
    float* buf_p   = buf_a + 2097152;           // 2,097,152 (proj f32 for LN res)
    bf16* a_bf     = (bf16*)(buf_p + 2097152);  // 2,097,152
    bf16* h_bf     = a_bf + 2097152;            // 2,097,152 (attn out / ffn hidden)
    bf16* qh       = h_bf + 2097152;            // 2,097,152
    bf16* kh       = qh + 2097152;              // 4,194,304
    bf16* vt       = kh + 4194304;              // 4,194,304 (V^T [bh][d][key])
    bf16* val_bf   = vt + 4194304;              // 4,194,304
    bf16* winb     = val_bf + 4194304;          // 3,145,728
    bf16* woutb    = winb + 3145728;            // 1,048,576
    bf16* w1b      = woutb + 1048576;           // 1,048,576
    bf16* w2b      = w1b + 1048576;             // 1,048,576
    // overlays (live only attn8 -> comb)
    float* pacc    = buf_a;                     // 4,194,304 f32 (buf_a..buf_p)
    float* pl      = (float*)a_bf;              // 131,072 f32 fits in a_bf

    const int MQ = NQ * BDIM;    // 4096
    // HD^-0.5 * log2(e): softmax then uses exp2 directly
    const float scaling = 0.125f * 1.44269504f;

    modall_k<<<8192, 256, 0, stream>>>(diff_ts, aw_attn, ab_attn, aw_ffn, ab_ffn, mod_ws);
    convall_k<<<10240, 256, 0, stream>>>(value, in_w, out_w, w1, w2,
                                         val_bf, winb, woutb, w1b, w2b);
    // aq for layer 0
    adaln_k<<<(MQ * CDIM) / 256, 256, 0, stream>>>(query, mod_ws, a_bf);

    for (int i = 0; i < LAYERS; ++i) {
        const float* mod_ffn  = mod_ws + i * 8192 + 4096;
        const float* mod_attn_next = (i + 1 < LAYERS) ? (mod_ws + (i + 1) * 8192) : nullptr;
        const bf16* winb_i = winb + (size_t)i * 1536 * CDIM;
        const float* in_b_i = in_b + (size_t)i * 1536;
        const float* qsrc = (i == 0) ? query : q_cur;

        // q proj: scale(log2e folded) + rotary -> qh head layout (consumes a_bf)
        mgemm8_k<2, true><<<256, 512, 0, stream>>>(
            a_bf, winb_i, in_b_i, qh, MQ, 512, CDIM, query_pos, scaling, NQ);
        // fused k + vT projection (8-wave): val staged once -> kh + vt
        kv8_k<<<512, 512, 0, stream>>>(
            val_bf, winb_i + (size_t)512 * CDIM, winb_i + (size_t)1024 * CDIM,
            in_b_i + 512, in_b_i + 1024, kh, vt, value_pos);
        // attention: 8-wave staged blocks, then combine -> h_bf
        attn8_k<<<512, 512, 0, stream>>>(qh, kh, vt, pl, pacc);
        attn_comb_k<<<2048, 256, 0, stream>>>(pl, pacc, h_bf);
        // out proj -> buf_p f32
        mgemm8_k<0, true><<<256, 512, 0, stream>>>(
            h_bf, woutb + (size_t)i * CDIM * CDIM, out_b + i * CDIM, buf_p,
            MQ, 512, CDIM, nullptr, 0.f, 0);
        // q' = LN1(q + o); xa = adaln_ffn(q') -> buf_a f32 + a_bf bf16
        ln_ad_k<<<MQ, 256, 0, stream>>>(qsrc, buf_p,
                                        ln1_g + i * CDIM, ln1_b + i * CDIM,
                                        mod_ffn, nullptr, nullptr, buf_a, a_bf);
        // ffn1 relu -> h_bf bf16
        mgemm8_k<1, true><<<256, 512, 0, stream>>>(
            a_bf, w1b + (size_t)i * CDIM * CDIM, b1 + i * CDIM, h_bf,
            MQ, 512, CDIM, nullptr, 0.f, 0);
        // ffn2 -> buf_p f32
        mgemm8_k<0, true><<<256, 512, 0, stream>>>(
            h_bf, w2b + (size_t)i * CDIM * CDIM, b2 + i * CDIM, buf_p,
            MQ, 512, CDIM, nullptr, 0.f, 0);
        // q = LN2(xa + h) -> q_cur + out chunk; aq(next) = adaln_attn(q) -> a_bf
        ln_ad_k<<<MQ, 256, 0, stream>>>(buf_a, buf_p,
                                        ln2_g + i * CDIM, ln2_b + i * CDIM,
                                        mod_attn_next, q_cur,
                                        out_f + (size_t)i * MQ * CDIM, nullptr, a_bf);
    }
}

// Round 10
// 669.398 us; speedup vs baseline: 1.0073x; 1.0073x over previous
//
#include <hip/hip_runtime.h>
#include <hip/hip_bf16.h>

typedef __hip_bfloat16 bf16;
typedef __attribute__((ext_vector_type(8))) short short8;
typedef __attribute__((ext_vector_type(4))) short s16x4;
typedef __attribute__((ext_vector_type(4))) float f32x4;

#define CDIM 512
#define BDIM 4
#define HDIM 8
#define HDQ  64
#define NQ   1024
#define NKV  2048
#define LAYERS 4
#define SPLIT 2

#if defined(__has_builtin)
#if __has_builtin(__builtin_amdgcn_global_load_lds)
#define USE_GLL 1
#endif
#endif

static __device__ __forceinline__ short f2s(float f) {
    bf16 h = __float2bfloat16(f);
    return *reinterpret_cast<short*>(&h);
}

// ---------------- elementwise / small kernels ----------------

__global__ __launch_bounds__(256) void convall_k(
    const float* __restrict__ s0, const float* __restrict__ s1,
    const float* __restrict__ s2, const float* __restrict__ s3,
    const float* __restrict__ s4,
    bf16* __restrict__ d0, bf16* __restrict__ d1, bf16* __restrict__ d2,
    bf16* __restrict__ d3, bf16* __restrict__ d4) {
    int gid = blockIdx.x * 256 + threadIdx.x;   // 2,621,440 total (x4 elems)
    const float* src; bf16* dst; int off;
    if (gid < 1048576)      { src = s0; dst = d0; off = gid; }
    else if (gid < 1835008) { src = s1; dst = d1; off = gid - 1048576; }
    else if (gid < 2097152) { src = s2; dst = d2; off = gid - 1835008; }
    else if (gid < 2359296) { src = s3; dst = d3; off = gid - 2097152; }
    else                    { src = s4; dst = d4; off = gid - 2359296; }
    f32x4 v = *(const f32x4*)(src + (size_t)off * 4);
    s16x4 o;
    o[0] = f2s(v[0]); o[1] = f2s(v[1]); o[2] = f2s(v[2]); o[3] = f2s(v[3]);
    *(s16x4*)(dst + (size_t)off * 4) = o;
}

// one wave per output row-dot (32768 waves); silu fused on the t-loads.
__global__ __launch_bounds__(256) void modall_k(const float* __restrict__ diff_ts,
    const float* __restrict__ aw_attn, const float* __restrict__ ab_attn,
    const float* __restrict__ aw_ffn,  const float* __restrict__ ab_ffn,
    float* __restrict__ mod) {
    int wv = blockIdx.x * 4 + (threadIdx.x >> 6);   // 32768 total
    int lane = threadIdx.x & 63;
    int col  = wv & 1023;
    int b    = (wv >> 10) & 3;
    int kind = (wv >> 12) & 1;
    int l    = wv >> 13;
    const float* w = (kind ? aw_ffn : aw_attn) + ((size_t)l * 1024 + col) * CDIM + lane * 8;
    const float* tb = diff_ts + b * CDIM + lane * 8;
    f32x4 w0 = *(const f32x4*)w;
    f32x4 w1 = *(const f32x4*)(w + 4);
    f32x4 t0 = *(const f32x4*)tb;
    f32x4 t1 = *(const f32x4*)(tb + 4);
    #pragma unroll
    for (int j = 0; j < 4; ++j) {
        t0[j] = t0[j] / (1.f + __expf(-t0[j]));
        t1[j] = t1[j] / (1.f + __expf(-t1[j]));
    }
    f32x4 pp = w0 * t0 + w1 * t1;
    float acc = (pp[0] + pp[1]) + (pp[2] + pp[3]);
    #pragma unroll
    for (int off = 32; off; off >>= 1) acc += __shfl_xor(acc, off);
    if (lane == 0)
        mod[wv] = acc + (kind ? ab_ffn : ab_attn)[l * 1024 + col];
}

// plain adaln (used once, for layer 0's aq from query)
__global__ __launch_bounds__(256) void adaln_k(const float* __restrict__ x,
                                               const float* __restrict__ mod,
                                               bf16* __restrict__ outb) {
    int i = blockIdx.x * 256 + threadIdx.x;  // 4096*512 total
    int c = i & 511;
    int b = (i >> 9) & 3;
    outb[i] = __float2bfloat16(x[i] * (1.f + mod[b * 1024 + c]) + mod[b * 1024 + 512 + c]);
}

// fused LayerNorm(x+res) [+ optional AdaLN of the LN output]
__global__ __launch_bounds__(256) void ln_ad_k(const float* __restrict__ x,
                                               const float* __restrict__ res,
                                               const float* __restrict__ g,
                                               const float* __restrict__ bb,
                                               const float* __restrict__ mod,
                                               float* __restrict__ ln_f,
                                               float* __restrict__ ln_f2,
                                               float* __restrict__ ad_f,
                                               bf16* __restrict__ ad_b) {
    int row = blockIdx.x;
    int t = threadIdx.x;
    size_t base = (size_t)row * CDIM;
    float v0 = x[base + t] + res[base + t];
    float v1 = x[base + t + 256] + res[base + t + 256];
    float s1 = v0 + v1;
    float s2 = v0 * v0 + v1 * v1;
    #pragma unroll
    for (int off = 32; off; off >>= 1) {
        s1 += __shfl_xor(s1, off);
        s2 += __shfl_xor(s2, off);
    }
    __shared__ float a1[4], a2[4];
    int w = t >> 6;
    if ((t & 63) == 0) { a1[w] = s1; a2[w] = s2; }
    __syncthreads();
    s1 = a1[0] + a1[1] + a1[2] + a1[3];
    s2 = a2[0] + a2[1] + a2[2] + a2[3];
    float mean = s1 * (1.f / 512.f);
    float var = s2 * (1.f / 512.f) - mean * mean;
    float rs = rsqrtf(var + 1e-5f);
    float y0 = (v0 - mean) * rs * g[t] + bb[t];
    float y1 = (v1 - mean) * rs * g[t + 256] + bb[t + 256];
    if (ln_f)  { ln_f[base + t] = y0;  ln_f[base + t + 256] = y1; }
    if (ln_f2) { ln_f2[base + t] = y0; ln_f2[base + t + 256] = y1; }
    if (mod) {
        int b = row & 3;
        float o0 = y0 * (1.f + mod[b * 1024 + t]) + mod[b * 1024 + 512 + t];
        float o1 = y1 * (1.f + mod[b * 1024 + t + 256]) + mod[b * 1024 + 512 + t + 256];
        if (ad_f) { ad_f[base + t] = o0; ad_f[base + t + 256] = o1; }
        ad_b[base + t] = __float2bfloat16(o0);
        ad_b[base + t + 256] = __float2bfloat16(o1);
    }
}

// ---------------- MFMA GEMM: out = A[MxK](bf16) * W[NxK](bf16)^T + bias -------
// 64x64 tile, BK=64 (two 32-col subtiles), double-buffered gll staging,
// LDS 16B-chunk swizzle (2-way banks), optional XCD-chunked work remap.
// ASRC 0: A is bf16 row-major (gll staged).
// ASRC 1: A is the attention partial buffers — 'A' points to pacc (f32
//         [2*32*NQ][64]) and 'pos' points to pl (f32 [2*32*NQ]); staging
//         combines the SPLIT partials, divides by the summed row-sums and
//         converts to bf16 in registers (fuses the old attn_comb kernel).
// EPI 0: (+bias[n]) -> f32
// EPI 1: relu(+bias[n]) -> bf16
// EPI 2: (+bias[n])*scl, rotary(pos) -> bf16 head layout (b,h,nseq,hd)
template <int EPI, int WM, int NT, bool SWZ, int ASRC>
__global__ __launch_bounds__(256) void mgemm_k(
    const bf16* __restrict__ A, const bf16* __restrict__ Wt,
    const float* __restrict__ bias, void* __restrict__ out0v,
    int M, int N, int K,
    const float* __restrict__ pos, float scl, int Nseq) {
    __shared__ bf16 As[2][2][64 * 32];   // [buf][ksub][row*32+chunk-swizzled col]
    __shared__ bf16 Bs[2][2][64 * 32];
    int t = threadIdx.x;
    int w = t >> 6;
    int lane = t & 63;
    int l16 = lane & 15;
    int quad = lane >> 4;
    int wy = w >> 1, wx = w & 1;

    int bxi, byi;
    if (SWZ) {
        int nx = gridDim.x, ny = gridDim.y;
        int flat = blockIdx.y * nx + blockIdx.x;
        int nwg = nx * ny;                  // multiple of 8 for all our grids
        int s = (flat & 7) * (nwg >> 3) + (flat >> 3);
        bxi = s % nx; byi = s / nx;
    } else {
        bxi = blockIdx.x; byi = blockIdx.y;
    }
    int bm = byi * 64;
    int bn = bxi * 64;

    int lr2 = lane >> 2;                         // staging row 0..15
    int lc4 = (lane & 3) ^ ((lane >> 3) & 3);    // pre-swizzled source chunk

    f32x4 acc[WM][NT] = {};

    auto stage = [&](int buf, int k0) {
        if (ASRC == 1) {
            // A: combine attn partials in registers -> bf16 -> swizzled LDS.
            // col = k0 + sub*32 + srcc*8 + j; h = col>>6 is constant per step.
            const float* pc  = (const float*)A;    // pacc
            const float* plp = pos;                // pl
            int h = k0 >> 6;
            for (int e = t; e < 512; e += 256) {
                int sub = e >> 8, c = e & 255;
                int row = c >> 2, c4 = c & 3;
                int srcc = c4 ^ ((row >> 1) & 3);
                int m = bm + row;
                int q = m >> 2, b = m & 3;
                int r1 = ((b * 8 + h) << 10) + q;      // (b*8+h)*NQ + q
                int r2 = 32 * NQ + r1;
                float rl = 1.f / (plp[r1] + plp[r2]);
                int dbase = sub * 32 + srcc * 8;
                f32x4 x0 = *(const f32x4*)&pc[(size_t)r1 * 64 + dbase];
                f32x4 x1 = *(const f32x4*)&pc[(size_t)r1 * 64 + dbase + 4];
                f32x4 y0 = *(const f32x4*)&pc[(size_t)r2 * 64 + dbase];
                f32x4 y1 = *(const f32x4*)&pc[(size_t)r2 * 64 + dbase + 4];
                short8 o;
                #pragma unroll
                for (int j = 0; j < 4; ++j) {
                    o[j]     = f2s((x0[j] + y0[j]) * rl);
                    o[j + 4] = f2s((x1[j] + y1[j]) * rl);
                }
                *(short8*)&As[buf][sub][row * 32 + c4 * 8] = o;
            }
#if USE_GLL
            const bf16* sb = Wt + (size_t)(bn + w * 16 + lr2) * K + k0 + lc4 * 8;
            #pragma unroll
            for (int j = 0; j < 2; ++j) {
                __builtin_amdgcn_global_load_lds(
                    (const unsigned int __attribute__((address_space(1)))*)(sb + j * 32),
                    (unsigned int __attribute__((address_space(3)))*)(&Bs[buf][j][w * 512]),
                    16, 0, 0);
            }
#else
            for (int e = t; e < 256; e += 256) {
                int c = e;
                // fallthrough handled below with full loop
            }
            for (int e = t; e < 512; e += 256) {
                int sub = e >> 8, c = e & 255;
                int row = c >> 2, c4 = c & 3;
                int srcc = c4 ^ ((row >> 1) & 3);
                *(uint4*)&Bs[buf][sub][row * 32 + c4 * 8] =
                    *(const uint4*)(Wt + (size_t)(bn + row) * K + k0 + sub * 32 + srcc * 8);
            }
#endif
        } else {
#if USE_GLL
            const bf16* sa = A + (size_t)(bm + w * 16 + lr2) * K + k0 + lc4 * 8;
            const bf16* sb = Wt + (size_t)(bn + w * 16 + lr2) * K + k0 + lc4 * 8;
            #pragma unroll
            for (int j = 0; j < 2; ++j) {
                __builtin_amdgcn_global_load_lds(
                    (const unsigned int __attribute__((address_space(1)))*)(sa + j * 32),
                    (unsigned int __attribute__((address_space(3)))*)(&As[buf][j][w * 512]),
                    16, 0, 0);
                __builtin_amdgcn_global_load_lds(
                    (const unsigned int __attribute__((address_space(1)))*)(sb + j * 32),
                    (unsigned int __attribute__((address_space(3)))*)(&Bs[buf][j][w * 512]),
                    16, 0, 0);
            }
#else
            for (int e = t; e < 512; e += 256) {
                int sub = e >> 8, c = e & 255;
                int row = c >> 2, c4 = c & 3;
                int srcc = c4 ^ ((row >> 1) & 3);
                *(uint4*)&As[buf][sub][row * 32 + c4 * 8] =
                    *(const uint4*)(A + (size_t)(bm + row) * K + k0 + sub * 32 + srcc * 8);
                *(uint4*)&Bs[buf][sub][row * 32 + c4 * 8] =
                    *(const uint4*)(Wt + (size_t)(bn + row) * K + k0 + sub * 32 + srcc * 8);
            }
#endif
        }
    };

    stage(0, 0);
    __syncthreads();   // drains vmcnt(0)/lgkm: tile 0 resident
    int cur = 0;
    int rchunk = (quad ^ ((l16 >> 1) & 3)) * 8;   // swizzled read col (elements)

    for (int k0 = 0; k0 < K; k0 += 64) {
        if (k0 + 64 < K) stage(cur ^ 1, k0 + 64);  // prefetch overlaps compute

        #pragma unroll
        for (int kk = 0; kk < 2; ++kk) {
            short8 af[WM], bfr[NT];
            #pragma unroll
            for (int mt = 0; mt < WM; ++mt)
                af[mt] = *(const short8*)
                    &As[cur][kk][((wy * WM + mt) * 16 + l16) * 32 + rchunk];
            #pragma unroll
            for (int nt = 0; nt < NT; ++nt)
                bfr[nt] = *(const short8*)
                    &Bs[cur][kk][((wx * NT + nt) * 16 + l16) * 32 + rchunk];
            #pragma unroll
            for (int mt = 0; mt < WM; ++mt)
                #pragma unroll
                for (int nt = 0; nt < NT; ++nt)
                    acc[mt][nt] = __builtin_amdgcn_mfma_f32_16x16x32_bf16(
                        af[mt], bfr[nt], acc[mt][nt], 0, 0, 0);
        }

        __syncthreads();   // prefetch landed, reads done
        cur ^= 1;
    }

    #pragma unroll
    for (int nt = 0; nt < NT; ++nt) {
        int n = bn + (wx * NT + nt) * 16 + l16;
        float bnv = bias[n];
        #pragma unroll
        for (int mt = 0; mt < WM; ++mt) {
            #pragma unroll
            for (int r = 0; r < 4; ++r) {
                int m = bm + (wy * WM + mt) * 16 + quad * 4 + r;
                float v = acc[mt][nt][r] + bnv;
                if (EPI == 0) {
                    ((float*)out0v)[(size_t)m * N + n] = v;
                } else if (EPI == 1) {
                    ((bf16*)out0v)[(size_t)m * N + n] = __float2bfloat16(fmaxf(v, 0.f));
                } else {  // EPI 2: rotary -> head layout
                    v *= scl;
                    int c = n;
                    int nseq = m >> 2, b = m & 3;
                    float part = __shfl_xor(v, 1);
                    const float* pp = pos + (((size_t)b * Nseq + nseq) * CDIM + c) * 2;
                    float cs = pp[0], sn = pp[1];
                    float o = (l16 & 1) ? (v * cs + part * sn) : (v * cs - part * sn);
                    bf16* op = (bf16*)out0v +
                               ((size_t)(b * HDIM + (c >> 6)) * Nseq + nseq) * HDQ + (c & 63);
                    *op = __float2bfloat16(o);
                }
            }
        }
    }
}

// ---------------- fused K + V^T projection, 8-wave 128x64 tile ----------------
// A = val_bf rows bm..bm+127 staged once for 8 waves; Bk/Bv 64-channel tiles.
__global__ __launch_bounds__(512) void kv8_k(
    const bf16* __restrict__ val, const bf16* __restrict__ Wk,
    const bf16* __restrict__ Wv, const float* __restrict__ biask,
    const float* __restrict__ biasv, bf16* __restrict__ kh,
    bf16* __restrict__ vt, const float* __restrict__ vpos) {
    __shared__ bf16 As[2][2][128 * 32];   // 32 KB
    __shared__ bf16 Bk[2][2][64 * 32];    // 16 KB
    __shared__ bf16 Bv[2][2][64 * 32];    // 16 KB
    int t = threadIdx.x;
    int w = t >> 6;
    int lane = t & 63;
    int l16 = lane & 15;
    int quad = lane >> 4;
    int wy = w >> 1, wx = w & 1;   // 4x2 wave grid

    // XCD-chunked: 512 blocks -> 64-block chunks; 8 consecutive s share bm
    int flat = blockIdx.x;
    int s = (flat & 7) * 64 + (flat >> 3);
    int bn = (s & 7) * 64;        // channel tile
    int bm = (s >> 3) * 128;      // val-row tile
    const int K = CDIM;

    int lr2 = lane >> 2;
    int lc4 = (lane & 3) ^ ((lane >> 3) & 3);

    f32x4 acck[2][2] = {};
    f32x4 accv[2][2] = {};

    auto stage = [&](int buf, int k0) {
#if USE_GLL
        const bf16* sa = val + (size_t)(bm + w * 16 + lr2) * K + k0 + lc4 * 8;
        #pragma unroll
        for (int j = 0; j < 2; ++j) {
            __builtin_amdgcn_global_load_lds(
                (const unsigned int __attribute__((address_space(1)))*)(sa + j * 32),
                (unsigned int __attribute__((address_space(3)))*)(&As[buf][j][w * 512]),
                16, 0, 0);
        }
        if (w < 4) {
            const bf16* sk = Wk + (size_t)(bn + w * 16 + lr2) * K + k0 + lc4 * 8;
            #pragma unroll
            for (int j = 0; j < 2; ++j) {
                __builtin_amdgcn_global_load_lds(
                    (const unsigned int __attribute__((address_space(1)))*)(sk + j * 32),
                    (unsigned int __attribute__((address_space(3)))*)(&Bk[buf][j][w * 512]),
                    16, 0, 0);
            }
        } else {
            const bf16* sv = Wv + (size_t)(bn + (w - 4) * 16 + lr2) * K + k0 + lc4 * 8;
            #pragma unroll
            for (int j = 0; j < 2; ++j) {
                __builtin_amdgcn_global_load_lds(
                    (const unsigned int __attribute__((address_space(1)))*)(sv + j * 32),
                    (unsigned int __attribute__((address_space(3)))*)(&Bv[buf][j][(w - 4) * 512]),
                    16, 0, 0);
            }
        }
#else
        for (int u = t; u < 1024; u += 512) {   // A: 2 ksub x 128 rows x 4 chunks
            int sub = u >> 9, c = u & 511;
            int row = c >> 2, c4 = c & 3;
            int srcc = c4 ^ ((row >> 1) & 3);
            *(uint4*)&As[buf][sub][row * 32 + c4 * 8] =
                *(const uint4*)(val + (size_t)(bm + row) * K + k0 + sub * 32 + srcc * 8);
        }
        {
            int u = t;                          // Bk/Bv: 512 units each
            int sub = u >> 8, c = u & 255;
            int row = c >> 2, c4 = c & 3;
            int srcc = c4 ^ ((row >> 1) & 3);
            *(uint4*)&Bk[buf][sub][row * 32 + c4 * 8] =
                *(const uint4*)(Wk + (size_t)(bn + row) * K + k0 + sub * 32 + srcc * 8);
            *(uint4*)&Bv[buf][sub][row * 32 + c4 * 8] =
                *(const uint4*)(Wv + (size_t)(bn + row) * K + k0 + sub * 32 + srcc * 8);
        }
#endif
    };

    stage(0, 0);
    __syncthreads();
    int cur = 0;
    int rchunk = (quad ^ ((l16 >> 1) & 3)) * 8;

    for (int k0 = 0; k0 < K; k0 += 64) {
        if (k0 + 64 < K) stage(cur ^ 1, k0 + 64);

        #pragma unroll
        for (int kk = 0; kk < 2; ++kk) {
            short8 af[2], bkf[2], bvf[2];
            #pragma unroll
            for (int mt = 0; mt < 2; ++mt)
                af[mt] = *(const short8*)
                    &As[cur][kk][(wy * 32 + mt * 16 + l16) * 32 + rchunk];
            #pragma unroll
            for (int nt = 0; nt < 2; ++nt) {
                bkf[nt] = *(const short8*)
                    &Bk[cur][kk][((wx * 2 + nt) * 16 + l16) * 32 + rchunk];
                bvf[nt] = *(const short8*)
                    &Bv[cur][kk][((wx * 2 + nt) * 16 + l16) * 32 + rchunk];
            }
            #pragma unroll
            for (int mt = 0; mt < 2; ++mt)
                #pragma unroll
                for (int nt = 0; nt < 2; ++nt) {
                    acck[mt][nt] = __builtin_amdgcn_mfma_f32_16x16x32_bf16(
                        af[mt], bkf[nt], acck[mt][nt], 0, 0, 0);
                    accv[mt][nt] = __builtin_amdgcn_mfma_f32_16x16x32_bf16(
                        af[mt], bvf[nt], accv[mt][nt], 0, 0, 0);
                }
        }

        __syncthreads();
        cur ^= 1;
    }

    #pragma unroll
    for (int nt = 0; nt < 2; ++nt) {
        int n = bn + (wx * 2 + nt) * 16 + l16;
        float bk_n = biask[n];
        float bv_n = biasv[n];
        int d = n & 63, hh = n >> 6;
        #pragma unroll
        for (int mt = 0; mt < 2; ++mt) {
            #pragma unroll
            for (int r = 0; r < 4; ++r) {
                int m = bm + wy * 32 + mt * 16 + quad * 4 + r;
                int nseq = m >> 2, b = m & 3;
                // K path: rotary -> head layout
                float v = acck[mt][nt][r] + bk_n;
                float part = __shfl_xor(v, 1);
                const float* pp = vpos + (((size_t)b * NKV + nseq) * CDIM + n) * 2;
                float cs = pp[0], sn = pp[1];
                float o = (l16 & 1) ? (v * cs + part * sn) : (v * cs - part * sn);
                kh[((size_t)(b * HDIM + hh) * NKV + nseq) * HDQ + d] =
                    __float2bfloat16(o);
                // V path: scatter transpose -> vt[bh][d][key]
                float vv = accv[mt][nt][r] + bv_n;
                vt[((size_t)(b * HDIM + hh) * HDQ + d) * NKV + nseq] =
                    __float2bfloat16(vv);
            }
        }
    }
}

// ---------------- MFMA flash attention v8: 8-wave blocks ----------------
__global__ __launch_bounds__(512) void attn8_k(const bf16* __restrict__ qh,
                                               const bf16* __restrict__ kh,
                                               const bf16* __restrict__ vT,
                                               float* __restrict__ pl,
                                               float* __restrict__ pacc) {
    __shared__ short Kb[2][64 * 64];   // [key][d], chunk-swizzled
    __shared__ short Vb[2][64 * 64];   // [d][key], chunk-swizzled
    __shared__ short Ps[8][16 * 64];   // per-wave P, chunk-swizzled
    int t = threadIdx.x;
    int wave = t >> 6, lane = t & 63;
    int l16 = lane & 15, quad = lane >> 4;

    // XCD swizzle: 512 blocks, 8 XCDs -> 64-block chunks. grp = bh*2+split.
    int b0 = blockIdx.x;
    int newid = (b0 & 7) * 64 + (b0 >> 3);
    int qtile = newid & 7;             // 8 q-tiles of 128 rows
    int grp = newid >> 3;
    int split = grp & 1;
    int bh = grp >> 1;
    int q0 = qtile * 128 + wave * 16;
    int kbase = split * (NKV / SPLIT);

    const bf16* qbase = qh + ((size_t)bh * NQ + q0) * HDQ;
    short8 aq0 = *(const short8*)(qbase + (size_t)l16 * HDQ + quad * 8);
    short8 aq1 = *(const short8*)(qbase + (size_t)l16 * HDQ + 32 + quad * 8);
    const bf16* kbh = kh + ((size_t)bh * NKV + kbase) * HDQ;
    const bf16* vbh = vT + (size_t)bh * HDQ * NKV + kbase;

    int r0 = wave * 8;             // this wave stages rows r0..r0+7 of K and V^T
    int lr = lane >> 3;            // row within the 8-row gll granule
    int swz_src = ((lane & 7) ^ lr) * 8;  // pre-swizzled source chunk (elements)

    auto stage = [&](int buf, int kt) {
#if USE_GLL
        __builtin_amdgcn_global_load_lds(
            (const unsigned int __attribute__((address_space(1)))*)
                (kbh + (size_t)(kt + r0 + lr) * HDQ + swz_src),
            (unsigned int __attribute__((address_space(3)))*)&Kb[buf][r0 * 64],
            16, 0, 0);
        __builtin_amdgcn_global_load_lds(
            (const unsigned int __attribute__((address_space(1)))*)
                (vbh + (size_t)(r0 + lr) * NKV + kt + swz_src),
            (unsigned int __attribute__((address_space(3)))*)&Vb[buf][r0 * 64],
            16, 0, 0);
#else
        int rr = r0 + lr;
        int lc = lane & 7;
        *(short8*)&Kb[buf][rr * 64 + ((lc ^ (rr & 7)) * 8)] =
            *(const short8*)(kbh + (size_t)(kt + rr) * HDQ + lc * 8);
        *(short8*)&Vb[buf][rr * 64 + ((lc ^ (rr & 7)) * 8)] =
            *(const short8*)(vbh + (size_t)rr * NKV + kt + lc * 8);
#endif
    };

    f32x4 accO[4] = {};
    float lsum[4] = {0.f, 0.f, 0.f, 0.f};

    stage(0, 0);
    __syncthreads();   // vmcnt(0) drain: tile 0 resident
    int cur = 0;
    int swz_m = l16 & 7;

    for (int kt = 0; kt < NKV / SPLIT; kt += 64) {
        if (kt + 64 < NKV / SPLIT) stage(cur ^ 1, kt + 64);  // prefetch

        // QK^T: S[16q x 64k]
        f32x4 sc[4] = {};
        #pragma unroll
        for (int nt = 0; nt < 4; ++nt) {
            const short* kr = &Kb[cur][(nt * 16 + l16) * 64];
            short8 bk0 = *(const short8*)&kr[(quad ^ swz_m) * 8];
            short8 bk1 = *(const short8*)&kr[((quad + 4) ^ swz_m) * 8];
            sc[nt] = __builtin_amdgcn_mfma_f32_16x16x32_bf16(aq0, bk0, sc[nt], 0, 0, 0);
            sc[nt] = __builtin_amdgcn_mfma_f32_16x16x32_bf16(aq1, bk1, sc[nt], 0, 0, 0);
        }

        // softmax numerators (no max; scores are O(1) by construction).
        // q already carries log2e, so exp2f directly.
        #pragma unroll
        for (int r = 0; r < 4; ++r) {
            float p0 = exp2f(sc[0][r]);
            float p1 = exp2f(sc[1][r]);
            float p2 = exp2f(sc[2][r]);
            float p3 = exp2f(sc[3][r]);
            lsum[r] += (p0 + p1) + (p2 + p3);
            int pr = quad * 4 + r;
            short* prow = &Ps[wave][pr * 64];
            int pm = pr & 7;
            int ch = l16 >> 3, kl = l16 & 7;
            prow[((ch ^ pm) << 3) + kl]       = f2s(p0);  // key l16       (chunk ch)
            prow[(((ch + 2) ^ pm) << 3) + kl] = f2s(p1);  // key 16+l16
            prow[(((ch + 4) ^ pm) << 3) + kl] = f2s(p2);  // key 32+l16
            prow[(((ch + 6) ^ pm) << 3) + kl] = f2s(p3);  // key 48+l16
        }

        // PV: O[16q x 64d] += P[16x64] * V[64x64]
        const short* prd = &Ps[wave][l16 * 64];
        short8 pa0 = *(const short8*)&prd[(quad ^ swz_m) * 8];
        short8 pa1 = *(const short8*)&prd[((quad + 4) ^ swz_m) * 8];
        #pragma unroll
        for (int nt = 0; nt < 4; ++nt) {
            const short* vr = &Vb[cur][(nt * 16 + l16) * 64];
            short8 bv0 = *(const short8*)&vr[(quad ^ swz_m) * 8];
            short8 bv1 = *(const short8*)&vr[((quad + 4) ^ swz_m) * 8];
            accO[nt] = __builtin_amdgcn_mfma_f32_16x16x32_bf16(pa0, bv0, accO[nt], 0, 0, 0);
            accO[nt] = __builtin_amdgcn_mfma_f32_16x16x32_bf16(pa1, bv1, accO[nt], 0, 0, 0);
        }

        __syncthreads();   // single barrier per tile; drains prefetch vmcnt
        cur ^= 1;
    }

    #pragma unroll
    for (int r = 0; r < 4; ++r) {
        #pragma unroll
        for (int off = 1; off < 16; off <<= 1) lsum[r] += __shfl_xor(lsum[r], off);
    }

    size_t rowbase = ((size_t)split * 32 + bh) * NQ + q0;
    #pragma unroll
    for (int r = 0; r < 4; ++r) {
        size_t row = rowbase + quad * 4 + r;
        if (l16 == 0) pl[row] = lsum[r];
        #pragma unroll
        for (int nt = 0; nt < 4; ++nt)
            pacc[row * 64 + nt * 16 + l16] = accO[nt][r];
    }
}

// ---------------- host side ----------------

extern "C" void kernel_launch(void* const* d_in, const int* in_sizes, int n_in,
                              void* d_out, int out_size, void* d_ws, size_t ws_size,
                              hipStream_t stream) {
    const float* query     = (const float*)d_in[0];
    const float* value     = (const float*)d_in[1];
    const float* diff_ts   = (const float*)d_in[2];
    const float* query_pos = (const float*)d_in[3];
    const float* value_pos = (const float*)d_in[4];
    const float* aw_attn   = (const float*)d_in[5];
    const float* ab_attn   = (const float*)d_in[6];
    const float* in_w      = (const float*)d_in[7];
    const float* in_b      = (const float*)d_in[8];
    const float* out_w     = (const float*)d_in[9];
    const float* out_b     = (const float*)d_in[10];
    const float* ln1_g     = (const float*)d_in[11];
    const float* ln1_b     = (const float*)d_in[12];
    const float* aw_ffn    = (const float*)d_in[13];
    const float* ab_ffn    = (const float*)d_in[14];
    const float* w1        = (const float*)d_in[15];
    const float* b1        = (const float*)d_in[16];
    const float* w2        = (const float*)d_in[17];
    const float* b2        = (const float*)d_in[18];
    const float* ln2_g     = (const float*)d_in[19];
    const float* ln2_b     = (const float*)d_in[20];
    float* out_f = (float*)d_out;

    float* ws      = (float*)d_ws;
    float* mod_ws  = ws + 2048;                 // 32768
    float* q_cur   = ws + 34816;                // 2,097,152
    float* buf_a   = q_cur + 2097152;           // 2,097,152 (xa f32 for LN2)
    float* buf_p   = buf_a + 2097152;           // 2,097,152 (proj f32 for LN res)
    bf16* a_bf     = (bf16*)(buf_p + 2097152);  // 2,097,152
    bf16* h_bf     = a_bf + 2097152;            // 2,097,152 (ffn hidden)
    bf16* qh       = h_bf + 2097152;            // 2,097,152
    bf16* kh       = qh + 2097152;              // 4,194,304
    bf16* vt       = kh + 4194304;              // 4,194,304 (V^T [bh][d][key])
    bf16* val_bf   = vt + 4194304;              // 4,194,304
    bf16* winb     = val_bf + 4194304;          // 3,145,728
    bf16* woutb    = winb + 3145728;            // 1,048,576
    bf16* w1b      = woutb + 1048576;           // 1,048,576
    bf16* w2b      = w1b + 1048576;             // 1,048,576
    // overlays (live attn8 -> out-proj)
    float* pacc    = buf_a;                     // 4,194,304 f32 (buf_a..buf_p)
    float* pl      = (float*)a_bf;              // 131,072 f32 fits in a_bf

    const int MQ = NQ * BDIM;    // 4096
    // HD^-0.5 * log2(e): softmax then uses exp2 directly
    const float scaling = 0.125f * 1.44269504f;

    modall_k<<<8192, 256, 0, stream>>>(diff_ts, aw_attn, ab_attn, aw_ffn, ab_ffn, mod_ws);
    convall_k<<<10240, 256, 0, stream>>>(value, in_w, out_w, w1, w2,
                                         val_bf, winb, woutb, w1b, w2b);
    // aq for layer 0
    adaln_k<<<(MQ * CDIM) / 256, 256, 0, stream>>>(query, mod_ws, a_bf);

    for (int i = 0; i < LAYERS; ++i) {
        const float* mod_ffn  = mod_ws + i * 8192 + 4096;
        const float* mod_attn_next = (i + 1 < LAYERS) ? (mod_ws + (i + 1) * 8192) : nullptr;
        const bf16* winb_i = winb + (size_t)i * 1536 * CDIM;
        const float* in_b_i = in_b + (size_t)i * 1536;
        const float* qsrc = (i == 0) ? query : q_cur;

        // q proj: scale(log2e folded) + rotary -> qh head layout (consumes a_bf)
        mgemm_k<2, 2, 2, true, 0><<<dim3(8, MQ / 64), 256, 0, stream>>>(
            a_bf, winb_i, in_b_i, qh, MQ, 512, CDIM, query_pos, scaling, NQ);
        // fused k + vT projection (8-wave): val staged once -> kh + vt
        kv8_k<<<512, 512, 0, stream>>>(
            val_bf, winb_i + (size_t)512 * CDIM, winb_i + (size_t)1024 * CDIM,
            in_b_i + 512, in_b_i + 1024, kh, vt, value_pos);
        // attention: 8-wave staged blocks -> split partials (pacc, pl)
        attn8_k<<<512, 512, 0, stream>>>(qh, kh, vt, pl, pacc);
        // out proj with fused partial-combine A-staging -> buf_p f32
        mgemm_k<0, 2, 2, true, 1><<<dim3(8, MQ / 64), 256, 0, stream>>>(
            (const bf16*)pacc, woutb + (size_t)i * CDIM * CDIM, out_b + i * CDIM,
            buf_p, MQ, 512, CDIM, pl, 0.f, 0);
        // q' = LN1(q + o); xa = adaln_ffn(q') -> buf_a f32 + a_bf bf16
        ln_ad_k<<<MQ, 256, 0, stream>>>(qsrc, buf_p,
                                        ln1_g + i * CDIM, ln1_b + i * CDIM,
                                        mod_ffn, nullptr, nullptr, buf_a, a_bf);
        // ffn1 relu -> h_bf bf16
        mgemm_k<1, 2, 2, true, 0><<<dim3(8, MQ / 64), 256, 0, stream>>>(
            a_bf, w1b + (size_t)i * CDIM * CDIM, b1 + i * CDIM, h_bf,
            MQ, 512, CDIM, nullptr, 0.f, 0);
        // ffn2 -> buf_p f32
        mgemm_k<0, 2, 2, true, 0><<<dim3(8, MQ / 64), 256, 0, stream>>>(
            h_bf, w2b + (size_t)i * CDIM * CDIM, b2 + i * CDIM, buf_p,
            MQ, 512, CDIM, nullptr, 0.f, 0);
        // q = LN2(xa + h) -> q_cur + out chunk; aq(next) = adaln_attn(q) -> a_bf
        ln_ad_k<<<MQ, 256, 0, stream>>>(buf_a, buf_p,
                                        ln2_g + i * CDIM, ln2_b + i * CDIM,
                                        mod_attn_next, q_cur,
                                        out_f + (size_t)i * MQ * CDIM, nullptr, a_bf);
    }
}

// Round 11
// 659.595 us; speedup vs baseline: 1.0223x; 1.0149x over previous
//
#include <hip/hip_runtime.h>
#include <hip/hip_bf16.h>

typedef __hip_bfloat16 bf16;
typedef __attribute__((ext_vector_type(8))) short short8;
typedef __attribute__((ext_vector_type(4))) short s16x4;
typedef __attribute__((ext_vector_type(4))) float f32x4;

#define CDIM 512
#define BDIM 4
#define HDIM 8
#define HDQ  64
#define NQ   1024
#define NKV  2048
#define LAYERS 4
#define SPLIT 2

#if defined(__has_builtin)
#if __has_builtin(__builtin_amdgcn_global_load_lds)
#define USE_GLL 1
#endif
#endif

static __device__ __forceinline__ short f2s(float f) {
    bf16 h = __float2bfloat16(f);
    return *reinterpret_cast<short*>(&h);
}

// ---------------- elementwise / small kernels ----------------

__global__ __launch_bounds__(256) void convall_k(
    const float* __restrict__ s0, const float* __restrict__ s1,
    const float* __restrict__ s2, const float* __restrict__ s3,
    const float* __restrict__ s4,
    bf16* __restrict__ d0, bf16* __restrict__ d1, bf16* __restrict__ d2,
    bf16* __restrict__ d3, bf16* __restrict__ d4) {
    int gid = blockIdx.x * 256 + threadIdx.x;   // 2,621,440 total (x4 elems)
    const float* src; bf16* dst; int off;
    if (gid < 1048576)      { src = s0; dst = d0; off = gid; }
    else if (gid < 1835008) { src = s1; dst = d1; off = gid - 1048576; }
    else if (gid < 2097152) { src = s2; dst = d2; off = gid - 1835008; }
    else if (gid < 2359296) { src = s3; dst = d3; off = gid - 2097152; }
    else                    { src = s4; dst = d4; off = gid - 2359296; }
    f32x4 v = *(const f32x4*)(src + (size_t)off * 4);
    s16x4 o;
    o[0] = f2s(v[0]); o[1] = f2s(v[1]); o[2] = f2s(v[2]); o[3] = f2s(v[3]);
    *(s16x4*)(dst + (size_t)off * 4) = o;
}

// one wave per output row-dot (32768 waves); silu fused on the t-loads.
__global__ __launch_bounds__(256) void modall_k(const float* __restrict__ diff_ts,
    const float* __restrict__ aw_attn, const float* __restrict__ ab_attn,
    const float* __restrict__ aw_ffn,  const float* __restrict__ ab_ffn,
    float* __restrict__ mod) {
    int wv = blockIdx.x * 4 + (threadIdx.x >> 6);   // 32768 total
    int lane = threadIdx.x & 63;
    int col  = wv & 1023;
    int b    = (wv >> 10) & 3;
    int kind = (wv >> 12) & 1;
    int l    = wv >> 13;
    const float* w = (kind ? aw_ffn : aw_attn) + ((size_t)l * 1024 + col) * CDIM + lane * 8;
    const float* tb = diff_ts + b * CDIM + lane * 8;
    f32x4 w0 = *(const f32x4*)w;
    f32x4 w1 = *(const f32x4*)(w + 4);
    f32x4 t0 = *(const f32x4*)tb;
    f32x4 t1 = *(const f32x4*)(tb + 4);
    #pragma unroll
    for (int j = 0; j < 4; ++j) {
        t0[j] = t0[j] / (1.f + __expf(-t0[j]));
        t1[j] = t1[j] / (1.f + __expf(-t1[j]));
    }
    f32x4 pp = w0 * t0 + w1 * t1;
    float acc = (pp[0] + pp[1]) + (pp[2] + pp[3]);
    #pragma unroll
    for (int off = 32; off; off >>= 1) acc += __shfl_xor(acc, off);
    if (lane == 0)
        mod[wv] = acc + (kind ? ab_ffn : ab_attn)[l * 1024 + col];
}

// plain adaln (used once, for layer 0's aq from query)
__global__ __launch_bounds__(256) void adaln_k(const float* __restrict__ x,
                                               const float* __restrict__ mod,
                                               bf16* __restrict__ outb) {
    int i = blockIdx.x * 256 + threadIdx.x;  // 4096*512 total
    int c = i & 511;
    int b = (i >> 9) & 3;
    outb[i] = __float2bfloat16(x[i] * (1.f + mod[b * 1024 + c]) + mod[b * 1024 + 512 + c]);
}

// fused LayerNorm(x+res) [+ optional AdaLN of the LN output]
__global__ __launch_bounds__(256) void ln_ad_k(const float* __restrict__ x,
                                               const float* __restrict__ res,
                                               const float* __restrict__ g,
                                               const float* __restrict__ bb,
                                               const float* __restrict__ mod,
                                               float* __restrict__ ln_f,
                                               float* __restrict__ ln_f2,
                                               float* __restrict__ ad_f,
                                               bf16* __restrict__ ad_b) {
    int row = blockIdx.x;
    int t = threadIdx.x;
    size_t base = (size_t)row * CDIM;
    float v0 = x[base + t] + res[base + t];
    float v1 = x[base + t + 256] + res[base + t + 256];
    float s1 = v0 + v1;
    float s2 = v0 * v0 + v1 * v1;
    #pragma unroll
    for (int off = 32; off; off >>= 1) {
        s1 += __shfl_xor(s1, off);
        s2 += __shfl_xor(s2, off);
    }
    __shared__ float a1[4], a2[4];
    int w = t >> 6;
    if ((t & 63) == 0) { a1[w] = s1; a2[w] = s2; }
    __syncthreads();
    s1 = a1[0] + a1[1] + a1[2] + a1[3];
    s2 = a2[0] + a2[1] + a2[2] + a2[3];
    float mean = s1 * (1.f / 512.f);
    float var = s2 * (1.f / 512.f) - mean * mean;
    float rs = rsqrtf(var + 1e-5f);
    float y0 = (v0 - mean) * rs * g[t] + bb[t];
    float y1 = (v1 - mean) * rs * g[t + 256] + bb[t + 256];
    if (ln_f)  { ln_f[base + t] = y0;  ln_f[base + t + 256] = y1; }
    if (ln_f2) { ln_f2[base + t] = y0; ln_f2[base + t + 256] = y1; }
    if (mod) {
        int b = row & 3;
        float o0 = y0 * (1.f + mod[b * 1024 + t]) + mod[b * 1024 + 512 + t];
        float o1 = y1 * (1.f + mod[b * 1024 + t + 256]) + mod[b * 1024 + 512 + t + 256];
        if (ad_f) { ad_f[base + t] = o0; ad_f[base + t + 256] = o1; }
        ad_b[base + t] = __float2bfloat16(o0);
        ad_b[base + t + 256] = __float2bfloat16(o1);
    }
}

// ---------------- MFMA GEMM: out = A[MxK](bf16) * W[NxK](bf16)^T + bias -------
// 64x64 tile, BK=64 (two 32-col subtiles), double-buffered gll staging,
// 2-way LDS chunk swizzle, XCD-chunked work remap.
// T4 counted-vmcnt pipeline: stage(next) -> s_waitcnt vmcnt(4) (cur tile's 4
// gll landed; next tile's stay in flight) -> raw s_barrier -> compute ->
// raw s_barrier. No vmcnt(0) drain in the main loop.
// EPI 0: (+bias[n]) -> f32
// EPI 1: relu(+bias[n]) -> bf16
// EPI 2: (+bias[n])*scl, rotary(pos) -> bf16 head layout (b,h,nseq,hd)
template <int EPI, int WM, int NT, bool SWZ>
__global__ __launch_bounds__(256) void mgemm_k(
    const bf16* __restrict__ A, const bf16* __restrict__ Wt,
    const float* __restrict__ bias, void* __restrict__ out0v,
    int M, int N, int K,
    const float* __restrict__ pos, float scl, int Nseq) {
    __shared__ bf16 As[2][2][64 * 32];   // [buf][ksub][row*32+chunk-swizzled col]
    __shared__ bf16 Bs[2][2][64 * 32];
    int t = threadIdx.x;
    int w = t >> 6;
    int lane = t & 63;
    int l16 = lane & 15;
    int quad = lane >> 4;
    int wy = w >> 1, wx = w & 1;

    int bxi, byi;
    if (SWZ) {
        int nx = gridDim.x, ny = gridDim.y;
        int flat = blockIdx.y * nx + blockIdx.x;
        int nwg = nx * ny;                  // multiple of 8 for all our grids
        int s = (flat & 7) * (nwg >> 3) + (flat >> 3);
        bxi = s % nx; byi = s / nx;
    } else {
        bxi = blockIdx.x; byi = blockIdx.y;
    }
    int bm = byi * 64;
    int bn = bxi * 64;

    int lr2 = lane >> 2;                         // staging row 0..15
    int lc4 = (lane & 3) ^ ((lane >> 3) & 3);    // pre-swizzled source chunk

    f32x4 acc[WM][NT] = {};

    auto stage = [&](int buf, int k0) {
#if USE_GLL
        const bf16* sa = A + (size_t)(bm + w * 16 + lr2) * K + k0 + lc4 * 8;
        const bf16* sb = Wt + (size_t)(bn + w * 16 + lr2) * K + k0 + lc4 * 8;
        #pragma unroll
        for (int j = 0; j < 2; ++j) {
            __builtin_amdgcn_global_load_lds(
                (const unsigned int __attribute__((address_space(1)))*)(sa + j * 32),
                (unsigned int __attribute__((address_space(3)))*)(&As[buf][j][w * 512]),
                16, 0, 0);
            __builtin_amdgcn_global_load_lds(
                (const unsigned int __attribute__((address_space(1)))*)(sb + j * 32),
                (unsigned int __attribute__((address_space(3)))*)(&Bs[buf][j][w * 512]),
                16, 0, 0);
        }
#else
        for (int e = t; e < 512; e += 256) {
            int sub = e >> 8, c = e & 255;
            int row = c >> 2, c4 = c & 3;
            int srcc = c4 ^ ((row >> 1) & 3);
            *(uint4*)&As[buf][sub][row * 32 + c4 * 8] =
                *(const uint4*)(A + (size_t)(bm + row) * K + k0 + sub * 32 + srcc * 8);
            *(uint4*)&Bs[buf][sub][row * 32 + c4 * 8] =
                *(const uint4*)(Wt + (size_t)(bn + row) * K + k0 + sub * 32 + srcc * 8);
        }
#endif
    };

    stage(0, 0);   // 4 gll in flight; first loop iteration waits for them
    int cur = 0;
    int rchunk = (quad ^ ((l16 >> 1) & 3)) * 8;   // swizzled read col (elements)

    for (int k0 = 0; k0 < K; k0 += 64) {
        bool more = (k0 + 64 < K);
        if (more) stage(cur ^ 1, k0 + 64);  // prefetch stays in flight across barriers
#if USE_GLL
        if (more) asm volatile("s_waitcnt vmcnt(4)" ::: "memory");
        else      asm volatile("s_waitcnt vmcnt(0)" ::: "memory");
        __builtin_amdgcn_s_barrier();
#else
        __syncthreads();
#endif

        #pragma unroll
        for (int kk = 0; kk < 2; ++kk) {
            short8 af[WM], bfr[NT];
            #pragma unroll
            for (int mt = 0; mt < WM; ++mt)
                af[mt] = *(const short8*)
                    &As[cur][kk][((wy * WM + mt) * 16 + l16) * 32 + rchunk];
            #pragma unroll
            for (int nt = 0; nt < NT; ++nt)
                bfr[nt] = *(const short8*)
                    &Bs[cur][kk][((wx * NT + nt) * 16 + l16) * 32 + rchunk];
            #pragma unroll
            for (int mt = 0; mt < WM; ++mt)
                #pragma unroll
                for (int nt = 0; nt < NT; ++nt)
                    acc[mt][nt] = __builtin_amdgcn_mfma_f32_16x16x32_bf16(
                        af[mt], bfr[nt], acc[mt][nt], 0, 0, 0);
        }

#if USE_GLL
        __builtin_amdgcn_s_barrier();   // all reads of buf[cur] done
#else
        __syncthreads();
#endif
        cur ^= 1;
    }

    #pragma unroll
    for (int nt = 0; nt < NT; ++nt) {
        int n = bn + (wx * NT + nt) * 16 + l16;
        float bnv = bias[n];
        #pragma unroll
        for (int mt = 0; mt < WM; ++mt) {
            #pragma unroll
            for (int r = 0; r < 4; ++r) {
                int m = bm + (wy * WM + mt) * 16 + quad * 4 + r;
                float v = acc[mt][nt][r] + bnv;
                if (EPI == 0) {
                    ((float*)out0v)[(size_t)m * N + n] = v;
                } else if (EPI == 1) {
                    ((bf16*)out0v)[(size_t)m * N + n] = __float2bfloat16(fmaxf(v, 0.f));
                } else {  // EPI 2: rotary -> head layout
                    v *= scl;
                    int c = n;
                    int nseq = m >> 2, b = m & 3;
                    float part = __shfl_xor(v, 1);
                    const float* pp = pos + (((size_t)b * Nseq + nseq) * CDIM + c) * 2;
                    float cs = pp[0], sn = pp[1];
                    float o = (l16 & 1) ? (v * cs + part * sn) : (v * cs - part * sn);
                    bf16* op = (bf16*)out0v +
                               ((size_t)(b * HDIM + (c >> 6)) * Nseq + nseq) * HDQ + (c & 63);
                    *op = __float2bfloat16(o);
                }
            }
        }
    }
}

// ---------------- fused K + V^T projection, 8-wave 128x64 tile ----------------
// A = val_bf rows bm..bm+127 staged once for 8 waves; Bk/Bv 64-channel tiles.
// Same T4 counted-vmcnt pipeline (4 gll/wave per stage).
__global__ __launch_bounds__(512) void kv8_k(
    const bf16* __restrict__ val, const bf16* __restrict__ Wk,
    const bf16* __restrict__ Wv, const float* __restrict__ biask,
    const float* __restrict__ biasv, bf16* __restrict__ kh,
    bf16* __restrict__ vt, const float* __restrict__ vpos) {
    __shared__ bf16 As[2][2][128 * 32];   // 32 KB
    __shared__ bf16 Bk[2][2][64 * 32];    // 16 KB
    __shared__ bf16 Bv[2][2][64 * 32];    // 16 KB
    int t = threadIdx.x;
    int w = t >> 6;
    int lane = t & 63;
    int l16 = lane & 15;
    int quad = lane >> 4;
    int wy = w >> 1, wx = w & 1;   // 4x2 wave grid

    // XCD-chunked: 512 blocks -> 64-block chunks; 8 consecutive s share bm
    int flat = blockIdx.x;
    int s = (flat & 7) * 64 + (flat >> 3);
    int bn = (s & 7) * 64;        // channel tile
    int bm = (s >> 3) * 128;      // val-row tile
    const int K = CDIM;

    int lr2 = lane >> 2;
    int lc4 = (lane & 3) ^ ((lane >> 3) & 3);

    f32x4 acck[2][2] = {};
    f32x4 accv[2][2] = {};

    auto stage = [&](int buf, int k0) {
#if USE_GLL
        const bf16* sa = val + (size_t)(bm + w * 16 + lr2) * K + k0 + lc4 * 8;
        #pragma unroll
        for (int j = 0; j < 2; ++j) {
            __builtin_amdgcn_global_load_lds(
                (const unsigned int __attribute__((address_space(1)))*)(sa + j * 32),
                (unsigned int __attribute__((address_space(3)))*)(&As[buf][j][w * 512]),
                16, 0, 0);
        }
        if (w < 4) {
            const bf16* sk = Wk + (size_t)(bn + w * 16 + lr2) * K + k0 + lc4 * 8;
            #pragma unroll
            for (int j = 0; j < 2; ++j) {
                __builtin_amdgcn_global_load_lds(
                    (const unsigned int __attribute__((address_space(1)))*)(sk + j * 32),
                    (unsigned int __attribute__((address_space(3)))*)(&Bk[buf][j][w * 512]),
                    16, 0, 0);
            }
        } else {
            const bf16* sv = Wv + (size_t)(bn + (w - 4) * 16 + lr2) * K + k0 + lc4 * 8;
            #pragma unroll
            for (int j = 0; j < 2; ++j) {
                __builtin_amdgcn_global_load_lds(
                    (const unsigned int __attribute__((address_space(1)))*)(sv + j * 32),
                    (unsigned int __attribute__((address_space(3)))*)(&Bv[buf][j][(w - 4) * 512]),
                    16, 0, 0);
            }
        }
#else
        for (int u = t; u < 1024; u += 512) {   // A: 2 ksub x 128 rows x 4 chunks
            int sub = u >> 9, c = u & 511;
            int row = c >> 2, c4 = c & 3;
            int srcc = c4 ^ ((row >> 1) & 3);
            *(uint4*)&As[buf][sub][row * 32 + c4 * 8] =
                *(const uint4*)(val + (size_t)(bm + row) * K + k0 + sub * 32 + srcc * 8);
        }
        {
            int u = t;                          // Bk/Bv: 512 units each
            int sub = u >> 8, c = u & 255;
            int row = c >> 2, c4 = c & 3;
            int srcc = c4 ^ ((row >> 1) & 3);
            *(uint4*)&Bk[buf][sub][row * 32 + c4 * 8] =
                *(const uint4*)(Wk + (size_t)(bn + row) * K + k0 + sub * 32 + srcc * 8);
            *(uint4*)&Bv[buf][sub][row * 32 + c4 * 8] =
                *(const uint4*)(Wv + (size_t)(bn + row) * K + k0 + sub * 32 + srcc * 8);
        }
#endif
    };

    stage(0, 0);
    int cur = 0;
    int rchunk = (quad ^ ((l16 >> 1) & 3)) * 8;

    for (int k0 = 0; k0 < K; k0 += 64) {
        bool more = (k0 + 64 < K);
        if (more) stage(cur ^ 1, k0 + 64);
#if USE_GLL
        if (more) asm volatile("s_waitcnt vmcnt(4)" ::: "memory");
        else      asm volatile("s_waitcnt vmcnt(0)" ::: "memory");
        __builtin_amdgcn_s_barrier();
#else
        __syncthreads();
#endif

        #pragma unroll
        for (int kk = 0; kk < 2; ++kk) {
            short8 af[2], bkf[2], bvf[2];
            #pragma unroll
            for (int mt = 0; mt < 2; ++mt)
                af[mt] = *(const short8*)
                    &As[cur][kk][(wy * 32 + mt * 16 + l16) * 32 + rchunk];
            #pragma unroll
            for (int nt = 0; nt < 2; ++nt) {
                bkf[nt] = *(const short8*)
                    &Bk[cur][kk][((wx * 2 + nt) * 16 + l16) * 32 + rchunk];
                bvf[nt] = *(const short8*)
                    &Bv[cur][kk][((wx * 2 + nt) * 16 + l16) * 32 + rchunk];
            }
            #pragma unroll
            for (int mt = 0; mt < 2; ++mt)
                #pragma unroll
                for (int nt = 0; nt < 2; ++nt) {
                    acck[mt][nt] = __builtin_amdgcn_mfma_f32_16x16x32_bf16(
                        af[mt], bkf[nt], acck[mt][nt], 0, 0, 0);
                    accv[mt][nt] = __builtin_amdgcn_mfma_f32_16x16x32_bf16(
                        af[mt], bvf[nt], accv[mt][nt], 0, 0, 0);
                }
        }

#if USE_GLL
        __builtin_amdgcn_s_barrier();
#else
        __syncthreads();
#endif
        cur ^= 1;
    }

    #pragma unroll
    for (int nt = 0; nt < 2; ++nt) {
        int n = bn + (wx * 2 + nt) * 16 + l16;
        float bk_n = biask[n];
        float bv_n = biasv[n];
        int d = n & 63, hh = n >> 6;
        #pragma unroll
        for (int mt = 0; mt < 2; ++mt) {
            #pragma unroll
            for (int r = 0; r < 4; ++r) {
                int m = bm + wy * 32 + mt * 16 + quad * 4 + r;
                int nseq = m >> 2, b = m & 3;
                // K path: rotary -> head layout
                float v = acck[mt][nt][r] + bk_n;
                float part = __shfl_xor(v, 1);
                const float* pp = vpos + (((size_t)b * NKV + nseq) * CDIM + n) * 2;
                float cs = pp[0], sn = pp[1];
                float o = (l16 & 1) ? (v * cs + part * sn) : (v * cs - part * sn);
                kh[((size_t)(b * HDIM + hh) * NKV + nseq) * HDQ + d] =
                    __float2bfloat16(o);
                // V path: scatter transpose -> vt[bh][d][key]
                float vv = accv[mt][nt][r] + bv_n;
                vt[((size_t)(b * HDIM + hh) * HDQ + d) * NKV + nseq] =
                    __float2bfloat16(vv);
            }
        }
    }
}

// ---------------- MFMA flash attention v9: 8-wave + counted vmcnt ----------------
// R8 structure, but the per-tile barrier no longer drains the prefetch:
// stage(next) -> vmcnt(2) (cur tile landed) -> s_barrier -> compute -> s_barrier.
__global__ __launch_bounds__(512) void attn8_k(const bf16* __restrict__ qh,
                                               const bf16* __restrict__ kh,
                                               const bf16* __restrict__ vT,
                                               float* __restrict__ pl,
                                               float* __restrict__ pacc) {
    __shared__ short Kb[2][64 * 64];   // [key][d], chunk-swizzled
    __shared__ short Vb[2][64 * 64];   // [d][key], chunk-swizzled
    __shared__ short Ps[8][16 * 64];   // per-wave P, chunk-swizzled
    int t = threadIdx.x;
    int wave = t >> 6, lane = t & 63;
    int l16 = lane & 15, quad = lane >> 4;

    // XCD swizzle: 512 blocks, 8 XCDs -> 64-block chunks. grp = bh*2+split.
    int b0 = blockIdx.x;
    int newid = (b0 & 7) * 64 + (b0 >> 3);
    int qtile = newid & 7;             // 8 q-tiles of 128 rows
    int grp = newid >> 3;
    int split = grp & 1;
    int bh = grp >> 1;
    int q0 = qtile * 128 + wave * 16;
    int kbase = split * (NKV / SPLIT);

    const bf16* qbase = qh + ((size_t)bh * NQ + q0) * HDQ;
    short8 aq0 = *(const short8*)(qbase + (size_t)l16 * HDQ + quad * 8);
    short8 aq1 = *(const short8*)(qbase + (size_t)l16 * HDQ + 32 + quad * 8);
    const bf16* kbh = kh + ((size_t)bh * NKV + kbase) * HDQ;
    const bf16* vbh = vT + (size_t)bh * HDQ * NKV + kbase;

    int r0 = wave * 8;             // this wave stages rows r0..r0+7 of K and V^T
    int lr = lane >> 3;            // row within the 8-row gll granule
    int swz_src = ((lane & 7) ^ lr) * 8;  // pre-swizzled source chunk (elements)

    auto stage = [&](int buf, int kt) {
#if USE_GLL
        __builtin_amdgcn_global_load_lds(
            (const unsigned int __attribute__((address_space(1)))*)
                (kbh + (size_t)(kt + r0 + lr) * HDQ + swz_src),
            (unsigned int __attribute__((address_space(3)))*)&Kb[buf][r0 * 64],
            16, 0, 0);
        __builtin_amdgcn_global_load_lds(
            (const unsigned int __attribute__((address_space(1)))*)
                (vbh + (size_t)(r0 + lr) * NKV + kt + swz_src),
            (unsigned int __attribute__((address_space(3)))*)&Vb[buf][r0 * 64],
            16, 0, 0);
#else
        int rr = r0 + lr;
        int lc = lane & 7;
        *(short8*)&Kb[buf][rr * 64 + ((lc ^ (rr & 7)) * 8)] =
            *(const short8*)(kbh + (size_t)(kt + rr) * HDQ + lc * 8);
        *(short8*)&Vb[buf][rr * 64 + ((lc ^ (rr & 7)) * 8)] =
            *(const short8*)(vbh + (size_t)rr * NKV + kt + lc * 8);
#endif
    };

    f32x4 accO[4] = {};
    float lsum[4] = {0.f, 0.f, 0.f, 0.f};

    stage(0, 0);   // 2 gll in flight; first iteration's vmcnt waits for them
    int cur = 0;
    int swz_m = l16 & 7;

    for (int kt = 0; kt < NKV / SPLIT; kt += 64) {
        bool more = (kt + 64 < NKV / SPLIT);
        if (more) stage(cur ^ 1, kt + 64);  // prefetch stays in flight
#if USE_GLL
        if (more) asm volatile("s_waitcnt vmcnt(2)" ::: "memory");
        else      asm volatile("s_waitcnt vmcnt(0)" ::: "memory");
        __builtin_amdgcn_s_barrier();
#else
        __syncthreads();
#endif

        // QK^T: S[16q x 64k]
        f32x4 sc[4] = {};
        #pragma unroll
        for (int nt = 0; nt < 4; ++nt) {
            const short* kr = &Kb[cur][(nt * 16 + l16) * 64];
            short8 bk0 = *(const short8*)&kr[(quad ^ swz_m) * 8];
            short8 bk1 = *(const short8*)&kr[((quad + 4) ^ swz_m) * 8];
            sc[nt] = __builtin_amdgcn_mfma_f32_16x16x32_bf16(aq0, bk0, sc[nt], 0, 0, 0);
            sc[nt] = __builtin_amdgcn_mfma_f32_16x16x32_bf16(aq1, bk1, sc[nt], 0, 0, 0);
        }

        // softmax numerators (no max; scores are O(1) by construction).
        // q already carries log2e, so exp2f directly.
        #pragma unroll
        for (int r = 0; r < 4; ++r) {
            float p0 = exp2f(sc[0][r]);
            float p1 = exp2f(sc[1][r]);
            float p2 = exp2f(sc[2][r]);
            float p3 = exp2f(sc[3][r]);
            lsum[r] += (p0 + p1) + (p2 + p3);
            int pr = quad * 4 + r;
            short* prow = &Ps[wave][pr * 64];
            int pm = pr & 7;
            int ch = l16 >> 3, kl = l16 & 7;
            prow[((ch ^ pm) << 3) + kl]       = f2s(p0);  // key l16       (chunk ch)
            prow[(((ch + 2) ^ pm) << 3) + kl] = f2s(p1);  // key 16+l16
            prow[(((ch + 4) ^ pm) << 3) + kl] = f2s(p2);  // key 32+l16
            prow[(((ch + 6) ^ pm) << 3) + kl] = f2s(p3);  // key 48+l16
        }

        // PV: O[16q x 64d] += P[16x64] * V[64x64]
        const short* prd = &Ps[wave][l16 * 64];
        short8 pa0 = *(const short8*)&prd[(quad ^ swz_m) * 8];
        short8 pa1 = *(const short8*)&prd[((quad + 4) ^ swz_m) * 8];
        #pragma unroll
        for (int nt = 0; nt < 4; ++nt) {
            const short* vr = &Vb[cur][(nt * 16 + l16) * 64];
            short8 bv0 = *(const short8*)&vr[(quad ^ swz_m) * 8];
            short8 bv1 = *(const short8*)&vr[((quad + 4) ^ swz_m) * 8];
            accO[nt] = __builtin_amdgcn_mfma_f32_16x16x32_bf16(pa0, bv0, accO[nt], 0, 0, 0);
            accO[nt] = __builtin_amdgcn_mfma_f32_16x16x32_bf16(pa1, bv1, accO[nt], 0, 0, 0);
        }

#if USE_GLL
        __builtin_amdgcn_s_barrier();   // all reads of buf[cur] done
#else
        __syncthreads();
#endif
        cur ^= 1;
    }

    #pragma unroll
    for (int r = 0; r < 4; ++r) {
        #pragma unroll
        for (int off = 1; off < 16; off <<= 1) lsum[r] += __shfl_xor(lsum[r], off);
    }

    size_t rowbase = ((size_t)split * 32 + bh) * NQ + q0;
    #pragma unroll
    for (int r = 0; r < 4; ++r) {
        size_t row = rowbase + quad * 4 + r;
        if (l16 == 0) pl[row] = lsum[r];
        #pragma unroll
        for (int nt = 0; nt < 4; ++nt)
            pacc[row * 64 + nt * 16 + l16] = accO[nt][r];
    }
}

// combine SPLIT partials -> bf16 attn output in (q, b, c) layout, x4 vectorized
__global__ __launch_bounds__(256) void attn_comb_k(const float* __restrict__ pl,
                                                   const float* __restrict__ pacc,
                                                   bf16* __restrict__ o) {
    int idx = blockIdx.x * 256 + threadIdx.x;   // 512K total (x4 elems)
    int d4 = (idx & 15) << 2;
    int row = idx >> 4;            // bh*NQ + q
    int q = row & (NQ - 1);
    int bh = row >> 10;
    const int S = 32 * NQ;
    float rl = 1.0f / (pl[row] + pl[S + row]);
    f32x4 a = *(const f32x4*)&pacc[(size_t)row * 64 + d4];
    f32x4 b = *(const f32x4*)&pacc[(size_t)(S + row) * 64 + d4];
    int bsel = bh >> 3, h = bh & 7;
    s16x4 o4;
    #pragma unroll
    for (int j = 0; j < 4; ++j) o4[j] = f2s((a[j] + b[j]) * rl);
    *(s16x4*)&o[((size_t)(q * BDIM + bsel)) * CDIM + h * HDQ + d4] = o4;
}

// ---------------- host side ----------------

extern "C" void kernel_launch(void* const* d_in, const int* in_sizes, int n_in,
                              void* d_out, int out_size, void* d_ws, size_t ws_size,
                              hipStream_t stream) {
    const float* query     = (const float*)d_in[0];
    const float* value     = (const float*)d_in[1];
    const float* diff_ts   = (const float*)d_in[2];
    const float* query_pos = (const float*)d_in[3];
    const float* value_pos = (const float*)d_in[4];
    const float* aw_attn   = (const float*)d_in[5];
    const float* ab_attn   = (const float*)d_in[6];
    const float* in_w      = (const float*)d_in[7];
    const float* in_b      = (const float*)d_in[8];
    const float* out_w     = (const float*)d_in[9];
    const float* out_b     = (const float*)d_in[10];
    const float* ln1_g     = (const float*)d_in[11];
    const float* ln1_b     = (const float*)d_in[12];
    const float* aw_ffn    = (const float*)d_in[13];
    const float* ab_ffn    = (const float*)d_in[14];
    const float* w1        = (const float*)d_in[15];
    const float* b1        = (const float*)d_in[16];
    const float* w2        = (const float*)d_in[17];
    const float* b2        = (const float*)d_in[18];
    const float* ln2_g     = (const float*)d_in[19];
    const float* ln2_b     = (const float*)d_in[20];
    float* out_f = (float*)d_out;

    float* ws      = (float*)d_ws;
    float* mod_ws  = ws + 2048;                 // 32768
    float* q_cur   = ws + 34816;                // 2,097,152
    float* buf_a   = q_cur + 2097152;           // 2,097,152 (xa f32 for LN2)
    float* buf_p   = buf_a + 2097152;           // 2,097,152 (proj f32 for LN res)
    bf16* a_bf     = (bf16*)(buf_p + 2097152);  // 2,097,152
    bf16* h_bf     = a_bf + 2097152;            // 2,097,152 (attn out / ffn hidden)
    bf16* qh       = h_bf + 2097152;            // 2,097,152
    bf16* kh       = qh + 2097152;              // 4,194,304
    bf16* vt       = kh + 4194304;              // 4,194,304 (V^T [bh][d][key])
    bf16* val_bf   = vt + 4194304;              // 4,194,304
    bf16* winb     = val_bf + 4194304;          // 3,145,728
    bf16* woutb    = winb + 3145728;            // 1,048,576
    bf16* w1b      = woutb + 1048576;           // 1,048,576
    bf16* w2b      = w1b + 1048576;             // 1,048,576
    // overlays (live only attn8 -> comb)
    float* pacc    = buf_a;                     // 4,194,304 f32 (buf_a..buf_p)
    float* pl      = (float*)a_bf;              // 131,072 f32 fits in a_bf

    const int MQ = NQ * BDIM;    // 4096
    // HD^-0.5 * log2(e): softmax then uses exp2 directly
    const float scaling = 0.125f * 1.44269504f;

    modall_k<<<8192, 256, 0, stream>>>(diff_ts, aw_attn, ab_attn, aw_ffn, ab_ffn, mod_ws);
    convall_k<<<10240, 256, 0, stream>>>(value, in_w, out_w, w1, w2,
                                         val_bf, winb, woutb, w1b, w2b);
    // aq for layer 0
    adaln_k<<<(MQ * CDIM) / 256, 256, 0, stream>>>(query, mod_ws, a_bf);

    for (int i = 0; i < LAYERS; ++i) {
        const float* mod_ffn  = mod_ws + i * 8192 + 4096;
        const float* mod_attn_next = (i + 1 < LAYERS) ? (mod_ws + (i + 1) * 8192) : nullptr;
        const bf16* winb_i = winb + (size_t)i * 1536 * CDIM;
        const float* in_b_i = in_b + (size_t)i * 1536;
        const float* qsrc = (i == 0) ? query : q_cur;

        // q proj: scale(log2e folded) + rotary -> qh head layout (consumes a_bf)
        mgemm_k<2, 2, 2, true><<<dim3(8, MQ / 64), 256, 0, stream>>>(
            a_bf, winb_i, in_b_i, qh, MQ, 512, CDIM, query_pos, scaling, NQ);
        // fused k + vT projection (8-wave): val staged once -> kh + vt
        kv8_k<<<512, 512, 0, stream>>>(
            val_bf, winb_i + (size_t)512 * CDIM, winb_i + (size_t)1024 * CDIM,
            in_b_i + 512, in_b_i + 1024, kh, vt, value_pos);
        // attention: 8-wave staged blocks, then combine -> h_bf
        attn8_k<<<512, 512, 0, stream>>>(qh, kh, vt, pl, pacc);
        attn_comb_k<<<2048, 256, 0, stream>>>(pl, pacc, h_bf);
        // out proj -> buf_p f32
        mgemm_k<0, 2, 2, true><<<dim3(8, MQ / 64), 256, 0, stream>>>(
            h_bf, woutb + (size_t)i * CDIM * CDIM, out_b + i * CDIM, buf_p,
            MQ, 512, CDIM, nullptr, 0.f, 0);
        // q' = LN1(q + o); xa = adaln_ffn(q') -> buf_a f32 + a_bf bf16
        ln_ad_k<<<MQ, 256, 0, stream>>>(qsrc, buf_p,
                                        ln1_g + i * CDIM, ln1_b + i * CDIM,
                                        mod_ffn, nullptr, nullptr, buf_a, a_bf);
        // ffn1 relu -> h_bf bf16
        mgemm_k<1, 2, 2, true><<<dim3(8, MQ / 64), 256, 0, stream>>>(
            a_bf, w1b + (size_t)i * CDIM * CDIM, b1 + i * CDIM, h_bf,
            MQ, 512, CDIM, nullptr, 0.f, 0);
        // ffn2 -> buf_p f32
        mgemm_k<0, 2, 2, true><<<dim3(8, MQ / 64), 256, 0, stream>>>(
            h_bf, w2b + (size_t)i * CDIM * CDIM, b2 + i * CDIM, buf_p,
            MQ, 512, CDIM, nullptr, 0.f, 0);
        // q = LN2(xa + h) -> q_cur + out chunk; aq(next) = adaln_attn(q) -> a_bf
        ln_ad_k<<<MQ, 256, 0, stream>>>(buf_a, buf_p,
                                        ln2_g + i * CDIM, ln2_b + i * CDIM,
                                        mod_attn_next, q_cur,
                                        out_f + (size_t)i * MQ * CDIM, nullptr, a_bf);
    }
}

// Round 12
// 633.230 us; speedup vs baseline: 1.0649x; 1.0416x over previous
//
#include <hip/hip_runtime.h>
#include <hip/hip_bf16.h>

typedef __hip_bfloat16 bf16;
typedef __attribute__((ext_vector_type(8))) short short8;
typedef __attribute__((ext_vector_type(4))) short s16x4;
typedef __attribute__((ext_vector_type(4))) float f32x4;

#define CDIM 512
#define BDIM 4
#define HDIM 8
#define HDQ  64
#define NQ   1024
#define NKV  2048
#define LAYERS 4
#define SPLIT 2

#if defined(__has_builtin)
#if __has_builtin(__builtin_amdgcn_global_load_lds)
#define USE_GLL 1
#endif
#endif

static __device__ __forceinline__ short f2s(float f) {
    bf16 h = __float2bfloat16(f);
    return *reinterpret_cast<short*>(&h);
}

// ---------------- elementwise / small kernels ----------------

__global__ __launch_bounds__(256) void convall_k(
    const float* __restrict__ s0, const float* __restrict__ s1,
    const float* __restrict__ s2, const float* __restrict__ s3,
    const float* __restrict__ s4,
    bf16* __restrict__ d0, bf16* __restrict__ d1, bf16* __restrict__ d2,
    bf16* __restrict__ d3, bf16* __restrict__ d4) {
    int gid = blockIdx.x * 256 + threadIdx.x;   // 2,621,440 total (x4 elems)
    const float* src; bf16* dst; int off;
    if (gid < 1048576)      { src = s0; dst = d0; off = gid; }
    else if (gid < 1835008) { src = s1; dst = d1; off = gid - 1048576; }
    else if (gid < 2097152) { src = s2; dst = d2; off = gid - 1835008; }
    else if (gid < 2359296) { src = s3; dst = d3; off = gid - 2097152; }
    else                    { src = s4; dst = d4; off = gid - 2359296; }
    f32x4 v = *(const f32x4*)(src + (size_t)off * 4);
    s16x4 o;
    o[0] = f2s(v[0]); o[1] = f2s(v[1]); o[2] = f2s(v[2]); o[3] = f2s(v[3]);
    *(s16x4*)(dst + (size_t)off * 4) = o;
}

// one wave per output row-dot (32768 waves); silu fused on the t-loads.
__global__ __launch_bounds__(256) void modall_k(const float* __restrict__ diff_ts,
    const float* __restrict__ aw_attn, const float* __restrict__ ab_attn,
    const float* __restrict__ aw_ffn,  const float* __restrict__ ab_ffn,
    float* __restrict__ mod) {
    int wv = blockIdx.x * 4 + (threadIdx.x >> 6);   // 32768 total
    int lane = threadIdx.x & 63;
    int col  = wv & 1023;
    int b    = (wv >> 10) & 3;
    int kind = (wv >> 12) & 1;
    int l    = wv >> 13;
    const float* w = (kind ? aw_ffn : aw_attn) + ((size_t)l * 1024 + col) * CDIM + lane * 8;
    const float* tb = diff_ts + b * CDIM + lane * 8;
    f32x4 w0 = *(const f32x4*)w;
    f32x4 w1 = *(const f32x4*)(w + 4);
    f32x4 t0 = *(const f32x4*)tb;
    f32x4 t1 = *(const f32x4*)(tb + 4);
    #pragma unroll
    for (int j = 0; j < 4; ++j) {
        t0[j] = t0[j] / (1.f + __expf(-t0[j]));
        t1[j] = t1[j] / (1.f + __expf(-t1[j]));
    }
    f32x4 pp = w0 * t0 + w1 * t1;
    float acc = (pp[0] + pp[1]) + (pp[2] + pp[3]);
    #pragma unroll
    for (int off = 32; off; off >>= 1) acc += __shfl_xor(acc, off);
    if (lane == 0)
        mod[wv] = acc + (kind ? ab_ffn : ab_attn)[l * 1024 + col];
}

// plain adaln (used once, for layer 0's aq from query)
__global__ __launch_bounds__(256) void adaln_k(const float* __restrict__ x,
                                               const float* __restrict__ mod,
                                               bf16* __restrict__ outb) {
    int i = blockIdx.x * 256 + threadIdx.x;  // 4096*512 total
    int c = i & 511;
    int b = (i >> 9) & 3;
    outb[i] = __float2bfloat16(x[i] * (1.f + mod[b * 1024 + c]) + mod[b * 1024 + 512 + c]);
}

// fused LayerNorm(x+res) [+ optional AdaLN of the LN output]
__global__ __launch_bounds__(256) void ln_ad_k(const float* __restrict__ x,
                                               const float* __restrict__ res,
                                               const float* __restrict__ g,
                                               const float* __restrict__ bb,
                                               const float* __restrict__ mod,
                                               float* __restrict__ ln_f,
                                               float* __restrict__ ln_f2,
                                               float* __restrict__ ad_f,
                                               bf16* __restrict__ ad_b) {
    int row = blockIdx.x;
    int t = threadIdx.x;
    size_t base = (size_t)row * CDIM;
    float v0 = x[base + t] + res[base + t];
    float v1 = x[base + t + 256] + res[base + t + 256];
    float s1 = v0 + v1;
    float s2 = v0 * v0 + v1 * v1;
    #pragma unroll
    for (int off = 32; off; off >>= 1) {
        s1 += __shfl_xor(s1, off);
        s2 += __shfl_xor(s2, off);
    }
    __shared__ float a1[4], a2[4];
    int w = t >> 6;
    if ((t & 63) == 0) { a1[w] = s1; a2[w] = s2; }
    __syncthreads();
    s1 = a1[0] + a1[1] + a1[2] + a1[3];
    s2 = a2[0] + a2[1] + a2[2] + a2[3];
    float mean = s1 * (1.f / 512.f);
    float var = s2 * (1.f / 512.f) - mean * mean;
    float rs = rsqrtf(var + 1e-5f);
    float y0 = (v0 - mean) * rs * g[t] + bb[t];
    float y1 = (v1 - mean) * rs * g[t + 256] + bb[t + 256];
    if (ln_f)  { ln_f[base + t] = y0;  ln_f[base + t + 256] = y1; }
    if (ln_f2) { ln_f2[base + t] = y0; ln_f2[base + t + 256] = y1; }
    if (mod) {
        int b = row & 3;
        float o0 = y0 * (1.f + mod[b * 1024 + t]) + mod[b * 1024 + 512 + t];
        float o1 = y1 * (1.f + mod[b * 1024 + t + 256]) + mod[b * 1024 + 512 + t + 256];
        if (ad_f) { ad_f[base + t] = o0; ad_f[base + t + 256] = o1; }
        ad_b[base + t] = __float2bfloat16(o0);
        ad_b[base + t + 256] = __float2bfloat16(o1);
    }
}

// ---------------- MFMA GEMM: out = A[MxK](bf16) * W[NxK](bf16)^T + bias -------
// 64x64 tile, BK=64 (two 32-col subtiles), double-buffered gll staging,
// 2-way LDS chunk swizzle, XCD-chunked work remap, counted-vmcnt pipeline.
// EPI 0: (+bias[n]) -> f32
// EPI 1: relu(+bias[n]) -> bf16
template <int EPI, int WM, int NT, bool SWZ>
__global__ __launch_bounds__(256) void mgemm_k(
    const bf16* __restrict__ A, const bf16* __restrict__ Wt,
    const float* __restrict__ bias, void* __restrict__ out0v,
    int M, int N, int K,
    const float* __restrict__ pos, float scl, int Nseq) {
    __shared__ bf16 As[2][2][64 * 32];   // [buf][ksub][row*32+chunk-swizzled col]
    __shared__ bf16 Bs[2][2][64 * 32];
    int t = threadIdx.x;
    int w = t >> 6;
    int lane = t & 63;
    int l16 = lane & 15;
    int quad = lane >> 4;
    int wy = w >> 1, wx = w & 1;

    int bxi, byi;
    if (SWZ) {
        int nx = gridDim.x, ny = gridDim.y;
        int flat = blockIdx.y * nx + blockIdx.x;
        int nwg = nx * ny;                  // multiple of 8 for all our grids
        int s = (flat & 7) * (nwg >> 3) + (flat >> 3);
        bxi = s % nx; byi = s / nx;
    } else {
        bxi = blockIdx.x; byi = blockIdx.y;
    }
    int bm = byi * 64;
    int bn = bxi * 64;

    int lr2 = lane >> 2;                         // staging row 0..15
    int lc4 = (lane & 3) ^ ((lane >> 3) & 3);    // pre-swizzled source chunk

    f32x4 acc[WM][NT] = {};

    auto stage = [&](int buf, int k0) {
#if USE_GLL
        const bf16* sa = A + (size_t)(bm + w * 16 + lr2) * K + k0 + lc4 * 8;
        const bf16* sb = Wt + (size_t)(bn + w * 16 + lr2) * K + k0 + lc4 * 8;
        #pragma unroll
        for (int j = 0; j < 2; ++j) {
            __builtin_amdgcn_global_load_lds(
                (const unsigned int __attribute__((address_space(1)))*)(sa + j * 32),
                (unsigned int __attribute__((address_space(3)))*)(&As[buf][j][w * 512]),
                16, 0, 0);
            __builtin_amdgcn_global_load_lds(
                (const unsigned int __attribute__((address_space(1)))*)(sb + j * 32),
                (unsigned int __attribute__((address_space(3)))*)(&Bs[buf][j][w * 512]),
                16, 0, 0);
        }
#else
        for (int e = t; e < 512; e += 256) {
            int sub = e >> 8, c = e & 255;
            int row = c >> 2, c4 = c & 3;
            int srcc = c4 ^ ((row >> 1) & 3);
            *(uint4*)&As[buf][sub][row * 32 + c4 * 8] =
                *(const uint4*)(A + (size_t)(bm + row) * K + k0 + sub * 32 + srcc * 8);
            *(uint4*)&Bs[buf][sub][row * 32 + c4 * 8] =
                *(const uint4*)(Wt + (size_t)(bn + row) * K + k0 + sub * 32 + srcc * 8);
        }
#endif
    };

    stage(0, 0);   // 4 gll in flight; first loop iteration waits for them
    int cur = 0;
    int rchunk = (quad ^ ((l16 >> 1) & 3)) * 8;   // swizzled read col (elements)

    for (int k0 = 0; k0 < K; k0 += 64) {
        bool more = (k0 + 64 < K);
        if (more) stage(cur ^ 1, k0 + 64);  // prefetch stays in flight across barriers
#if USE_GLL
        if (more) asm volatile("s_waitcnt vmcnt(4)" ::: "memory");
        else      asm volatile("s_waitcnt vmcnt(0)" ::: "memory");
        __builtin_amdgcn_s_barrier();
#else
        __syncthreads();
#endif

        #pragma unroll
        for (int kk = 0; kk < 2; ++kk) {
            short8 af[WM], bfr[NT];
            #pragma unroll
            for (int mt = 0; mt < WM; ++mt)
                af[mt] = *(const short8*)
                    &As[cur][kk][((wy * WM + mt) * 16 + l16) * 32 + rchunk];
            #pragma unroll
            for (int nt = 0; nt < NT; ++nt)
                bfr[nt] = *(const short8*)
                    &Bs[cur][kk][((wx * NT + nt) * 16 + l16) * 32 + rchunk];
            #pragma unroll
            for (int mt = 0; mt < WM; ++mt)
                #pragma unroll
                for (int nt = 0; nt < NT; ++nt)
                    acc[mt][nt] = __builtin_amdgcn_mfma_f32_16x16x32_bf16(
                        af[mt], bfr[nt], acc[mt][nt], 0, 0, 0);
        }

#if USE_GLL
        __builtin_amdgcn_s_barrier();   // all reads of buf[cur] done
#else
        __syncthreads();
#endif
        cur ^= 1;
    }

    #pragma unroll
    for (int nt = 0; nt < NT; ++nt) {
        int n = bn + (wx * NT + nt) * 16 + l16;
        float bnv = bias[n];
        #pragma unroll
        for (int mt = 0; mt < WM; ++mt) {
            #pragma unroll
            for (int r = 0; r < 4; ++r) {
                int m = bm + (wy * WM + mt) * 16 + quad * 4 + r;
                float v = acc[mt][nt][r] + bnv;
                if (EPI == 0) {
                    ((float*)out0v)[(size_t)m * N + n] = v;
                } else {  // EPI 1
                    ((bf16*)out0v)[(size_t)m * N + n] = __float2bfloat16(fmaxf(v, 0.f));
                }
            }
        }
    }
}

// ---------------- merged Q + K + V^T projection, 8-wave 128x64 tiles ----------
// Blocks 0..511:   kv work — A=val_bf slab (128 rows) staged once; Bk+Bv tiles;
//                  epilogues: kh=rotary(val@Wk^T+bk), vt=(val@Wv^T+bv) scatter-T.
// Blocks 512..767: q-proj — A=a_bf slab (128 rows); Bq tile; epilogue:
//                  qh = rotary((a_bf@Wq^T+bq)*scl) head layout.
// Each section keeps its own XCD-chunked remap (A-panel sharers -> one XCD).
// Counted-vmcnt pipeline; per-wave gll counts: kv=4, qproj w<4:4 / w>=4:2.
__global__ __launch_bounds__(512) void qkv8_k(
    const bf16* __restrict__ a_bf, const bf16* __restrict__ val,
    const bf16* __restrict__ winb_i, const float* __restrict__ in_b_i,
    bf16* __restrict__ qh, bf16* __restrict__ kh, bf16* __restrict__ vt,
    const float* __restrict__ qpos, const float* __restrict__ vpos,
    float scaling) {
    __shared__ bf16 As[2][2][128 * 32];   // 32 KB (both sections)
    __shared__ bf16 B0[2][2][64 * 32];    // 16 KB (Bk / Bq)
    __shared__ bf16 B1[2][2][64 * 32];    // 16 KB (Bv / unused)
    int t = threadIdx.x;
    int w = t >> 6;
    int lane = t & 63;
    int l16 = lane & 15;
    int quad = lane >> 4;
    int wy = w >> 1, wx = w & 1;   // 4x2 wave grid
    const int K = CDIM;

    bool isq = (blockIdx.x >= 512);
    int bm, bn;
    const bf16 *Aptr, *W0, *W1;
    if (isq) {
        int flat = blockIdx.x - 512;          // 256 blocks: 32 m x 8 n
        int s = (flat & 7) * 32 + (flat >> 3);
        bn = (s & 7) * 64; bm = (s >> 3) * 128;
        Aptr = a_bf; W0 = winb_i; W1 = nullptr;
    } else {
        int flat = blockIdx.x;                // 512 blocks: 64 m x 8 n
        int s = (flat & 7) * 64 + (flat >> 3);
        bn = (s & 7) * 64; bm = (s >> 3) * 128;
        Aptr = val; W0 = winb_i + (size_t)512 * CDIM; W1 = winb_i + (size_t)1024 * CDIM;
    }

    int lr2 = lane >> 2;
    int lc4 = (lane & 3) ^ ((lane >> 3) & 3);

    auto stage = [&](int buf, int k0) {
#if USE_GLL
        const bf16* sa = Aptr + (size_t)(bm + w * 16 + lr2) * K + k0 + lc4 * 8;
        #pragma unroll
        for (int j = 0; j < 2; ++j) {
            __builtin_amdgcn_global_load_lds(
                (const unsigned int __attribute__((address_space(1)))*)(sa + j * 32),
                (unsigned int __attribute__((address_space(3)))*)(&As[buf][j][w * 512]),
                16, 0, 0);
        }
        if (w < 4) {
            const bf16* sk = W0 + (size_t)(bn + w * 16 + lr2) * K + k0 + lc4 * 8;
            #pragma unroll
            for (int j = 0; j < 2; ++j) {
                __builtin_amdgcn_global_load_lds(
                    (const unsigned int __attribute__((address_space(1)))*)(sk + j * 32),
                    (unsigned int __attribute__((address_space(3)))*)(&B0[buf][j][w * 512]),
                    16, 0, 0);
            }
        } else if (!isq) {
            const bf16* sv = W1 + (size_t)(bn + (w - 4) * 16 + lr2) * K + k0 + lc4 * 8;
            #pragma unroll
            for (int j = 0; j < 2; ++j) {
                __builtin_amdgcn_global_load_lds(
                    (const unsigned int __attribute__((address_space(1)))*)(sv + j * 32),
                    (unsigned int __attribute__((address_space(3)))*)(&B1[buf][j][(w - 4) * 512]),
                    16, 0, 0);
            }
        }
#else
        for (int u = t; u < 1024; u += 512) {   // A: 2 ksub x 128 rows x 4 chunks
            int sub = u >> 9, c = u & 511;
            int row = c >> 2, c4 = c & 3;
            int srcc = c4 ^ ((row >> 1) & 3);
            *(uint4*)&As[buf][sub][row * 32 + c4 * 8] =
                *(const uint4*)(Aptr + (size_t)(bm + row) * K + k0 + sub * 32 + srcc * 8);
        }
        {
            int u = t;
            int sub = u >> 8, c = u & 255;
            int row = c >> 2, c4 = c & 3;
            int srcc = c4 ^ ((row >> 1) & 3);
            *(uint4*)&B0[buf][sub][row * 32 + c4 * 8] =
                *(const uint4*)(W0 + (size_t)(bn + row) * K + k0 + sub * 32 + srcc * 8);
            if (!isq)
                *(uint4*)&B1[buf][sub][row * 32 + c4 * 8] =
                    *(const uint4*)(W1 + (size_t)(bn + row) * K + k0 + sub * 32 + srcc * 8);
        }
#endif
    };

    int rchunk = (quad ^ ((l16 >> 1) & 3)) * 8;
    stage(0, 0);
    int cur = 0;

    if (isq) {
        f32x4 acc[2][2] = {};
        for (int k0 = 0; k0 < K; k0 += 64) {
            bool more = (k0 + 64 < K);
            if (more) stage(cur ^ 1, k0 + 64);
#if USE_GLL
            if (more) {
                if (w < 4) asm volatile("s_waitcnt vmcnt(4)" ::: "memory");
                else       asm volatile("s_waitcnt vmcnt(2)" ::: "memory");
            } else {
                asm volatile("s_waitcnt vmcnt(0)" ::: "memory");
            }
            __builtin_amdgcn_s_barrier();
#else
            __syncthreads();
#endif
            #pragma unroll
            for (int kk = 0; kk < 2; ++kk) {
                short8 af[2], bfr[2];
                #pragma unroll
                for (int mt = 0; mt < 2; ++mt)
                    af[mt] = *(const short8*)
                        &As[cur][kk][(wy * 32 + mt * 16 + l16) * 32 + rchunk];
                #pragma unroll
                for (int nt = 0; nt < 2; ++nt)
                    bfr[nt] = *(const short8*)
                        &B0[cur][kk][((wx * 2 + nt) * 16 + l16) * 32 + rchunk];
                #pragma unroll
                for (int mt = 0; mt < 2; ++mt)
                    #pragma unroll
                    for (int nt = 0; nt < 2; ++nt)
                        acc[mt][nt] = __builtin_amdgcn_mfma_f32_16x16x32_bf16(
                            af[mt], bfr[nt], acc[mt][nt], 0, 0, 0);
            }
#if USE_GLL
            __builtin_amdgcn_s_barrier();
#else
            __syncthreads();
#endif
            cur ^= 1;
        }

        #pragma unroll
        for (int nt = 0; nt < 2; ++nt) {
            int n = bn + (wx * 2 + nt) * 16 + l16;
            float bnv = in_b_i[n];
            #pragma unroll
            for (int mt = 0; mt < 2; ++mt) {
                #pragma unroll
                for (int r = 0; r < 4; ++r) {
                    int m = bm + wy * 32 + mt * 16 + quad * 4 + r;
                    float v = (acc[mt][nt][r] + bnv) * scaling;
                    int nseq = m >> 2, b = m & 3;
                    float part = __shfl_xor(v, 1);
                    const float* pp = qpos + (((size_t)b * NQ + nseq) * CDIM + n) * 2;
                    float cs = pp[0], sn = pp[1];
                    float o = (l16 & 1) ? (v * cs + part * sn) : (v * cs - part * sn);
                    qh[((size_t)(b * HDIM + (n >> 6)) * NQ + nseq) * HDQ + (n & 63)] =
                        __float2bfloat16(o);
                }
            }
        }
    } else {
        f32x4 acck[2][2] = {};
        f32x4 accv[2][2] = {};
        for (int k0 = 0; k0 < K; k0 += 64) {
            bool more = (k0 + 64 < K);
            if (more) stage(cur ^ 1, k0 + 64);
#if USE_GLL
            if (more) asm volatile("s_waitcnt vmcnt(4)" ::: "memory");
            else      asm volatile("s_waitcnt vmcnt(0)" ::: "memory");
            __builtin_amdgcn_s_barrier();
#else
            __syncthreads();
#endif
            #pragma unroll
            for (int kk = 0; kk < 2; ++kk) {
                short8 af[2], bkf[2], bvf[2];
                #pragma unroll
                for (int mt = 0; mt < 2; ++mt)
                    af[mt] = *(const short8*)
                        &As[cur][kk][(wy * 32 + mt * 16 + l16) * 32 + rchunk];
                #pragma unroll
                for (int nt = 0; nt < 2; ++nt) {
                    bkf[nt] = *(const short8*)
                        &B0[cur][kk][((wx * 2 + nt) * 16 + l16) * 32 + rchunk];
                    bvf[nt] = *(const short8*)
                        &B1[cur][kk][((wx * 2 + nt) * 16 + l16) * 32 + rchunk];
                }
                #pragma unroll
                for (int mt = 0; mt < 2; ++mt)
                    #pragma unroll
                    for (int nt = 0; nt < 2; ++nt) {
                        acck[mt][nt] = __builtin_amdgcn_mfma_f32_16x16x32_bf16(
                            af[mt], bkf[nt], acck[mt][nt], 0, 0, 0);
                        accv[mt][nt] = __builtin_amdgcn_mfma_f32_16x16x32_bf16(
                            af[mt], bvf[nt], accv[mt][nt], 0, 0, 0);
                    }
            }
#if USE_GLL
            __builtin_amdgcn_s_barrier();
#else
            __syncthreads();
#endif
            cur ^= 1;
        }

        #pragma unroll
        for (int nt = 0; nt < 2; ++nt) {
            int n = bn + (wx * 2 + nt) * 16 + l16;
            float bk_n = in_b_i[512 + n];
            float bv_n = in_b_i[1024 + n];
            int d = n & 63, hh = n >> 6;
            #pragma unroll
            for (int mt = 0; mt < 2; ++mt) {
                #pragma unroll
                for (int r = 0; r < 4; ++r) {
                    int m = bm + wy * 32 + mt * 16 + quad * 4 + r;
                    int nseq = m >> 2, b = m & 3;
                    // K path: rotary -> head layout
                    float v = acck[mt][nt][r] + bk_n;
                    float part = __shfl_xor(v, 1);
                    const float* pp = vpos + (((size_t)b * NKV + nseq) * CDIM + n) * 2;
                    float cs = pp[0], sn = pp[1];
                    float o = (l16 & 1) ? (v * cs + part * sn) : (v * cs - part * sn);
                    kh[((size_t)(b * HDIM + hh) * NKV + nseq) * HDQ + d] =
                        __float2bfloat16(o);
                    // V path: scatter transpose -> vt[bh][d][key]
                    float vv = accv[mt][nt][r] + bv_n;
                    vt[((size_t)(b * HDIM + hh) * HDQ + d) * NKV + nseq] =
                        __float2bfloat16(vv);
                }
            }
        }
    }
}

// ---------------- MFMA flash attention v9: 8-wave + counted vmcnt ----------------
__global__ __launch_bounds__(512) void attn8_k(const bf16* __restrict__ qh,
                                               const bf16* __restrict__ kh,
                                               const bf16* __restrict__ vT,
                                               float* __restrict__ pl,
                                               float* __restrict__ pacc) {
    __shared__ short Kb[2][64 * 64];   // [key][d], chunk-swizzled
    __shared__ short Vb[2][64 * 64];   // [d][key], chunk-swizzled
    __shared__ short Ps[8][16 * 64];   // per-wave P, chunk-swizzled
    int t = threadIdx.x;
    int wave = t >> 6, lane = t & 63;
    int l16 = lane & 15, quad = lane >> 4;

    // XCD swizzle: 512 blocks, 8 XCDs -> 64-block chunks. grp = bh*2+split.
    int b0 = blockIdx.x;
    int newid = (b0 & 7) * 64 + (b0 >> 3);
    int qtile = newid & 7;             // 8 q-tiles of 128 rows
    int grp = newid >> 3;
    int split = grp & 1;
    int bh = grp >> 1;
    int q0 = qtile * 128 + wave * 16;
    int kbase = split * (NKV / SPLIT);

    const bf16* qbase = qh + ((size_t)bh * NQ + q0) * HDQ;
    short8 aq0 = *(const short8*)(qbase + (size_t)l16 * HDQ + quad * 8);
    short8 aq1 = *(const short8*)(qbase + (size_t)l16 * HDQ + 32 + quad * 8);
    const bf16* kbh = kh + ((size_t)bh * NKV + kbase) * HDQ;
    const bf16* vbh = vT + (size_t)bh * HDQ * NKV + kbase;

    int r0 = wave * 8;             // this wave stages rows r0..r0+7 of K and V^T
    int lr = lane >> 3;            // row within the 8-row gll granule
    int swz_src = ((lane & 7) ^ lr) * 8;  // pre-swizzled source chunk (elements)

    auto stage = [&](int buf, int kt) {
#if USE_GLL
        __builtin_amdgcn_global_load_lds(
            (const unsigned int __attribute__((address_space(1)))*)
                (kbh + (size_t)(kt + r0 + lr) * HDQ + swz_src),
            (unsigned int __attribute__((address_space(3)))*)&Kb[buf][r0 * 64],
            16, 0, 0);
        __builtin_amdgcn_global_load_lds(
            (const unsigned int __attribute__((address_space(1)))*)
                (vbh + (size_t)(r0 + lr) * NKV + kt + swz_src),
            (unsigned int __attribute__((address_space(3)))*)&Vb[buf][r0 * 64],
            16, 0, 0);
#else
        int rr = r0 + lr;
        int lc = lane & 7;
        *(short8*)&Kb[buf][rr * 64 + ((lc ^ (rr & 7)) * 8)] =
            *(const short8*)(kbh + (size_t)(kt + rr) * HDQ + lc * 8);
        *(short8*)&Vb[buf][rr * 64 + ((lc ^ (rr & 7)) * 8)] =
            *(const short8*)(vbh + (size_t)rr * NKV + kt + lc * 8);
#endif
    };

    f32x4 accO[4] = {};
    float lsum[4] = {0.f, 0.f, 0.f, 0.f};

    stage(0, 0);   // 2 gll in flight; first iteration's vmcnt waits for them
    int cur = 0;
    int swz_m = l16 & 7;

    for (int kt = 0; kt < NKV / SPLIT; kt += 64) {
        bool more = (kt + 64 < NKV / SPLIT);
        if (more) stage(cur ^ 1, kt + 64);  // prefetch stays in flight
#if USE_GLL
        if (more) asm volatile("s_waitcnt vmcnt(2)" ::: "memory");
        else      asm volatile("s_waitcnt vmcnt(0)" ::: "memory");
        __builtin_amdgcn_s_barrier();
#else
        __syncthreads();
#endif

        // QK^T: S[16q x 64k]
        f32x4 sc[4] = {};
        #pragma unroll
        for (int nt = 0; nt < 4; ++nt) {
            const short* kr = &Kb[cur][(nt * 16 + l16) * 64];
            short8 bk0 = *(const short8*)&kr[(quad ^ swz_m) * 8];
            short8 bk1 = *(const short8*)&kr[((quad + 4) ^ swz_m) * 8];
            sc[nt] = __builtin_amdgcn_mfma_f32_16x16x32_bf16(aq0, bk0, sc[nt], 0, 0, 0);
            sc[nt] = __builtin_amdgcn_mfma_f32_16x16x32_bf16(aq1, bk1, sc[nt], 0, 0, 0);
        }

        // softmax numerators (no max; scores are O(1) by construction).
        // q already carries log2e, so exp2f directly.
        #pragma unroll
        for (int r = 0; r < 4; ++r) {
            float p0 = exp2f(sc[0][r]);
            float p1 = exp2f(sc[1][r]);
            float p2 = exp2f(sc[2][r]);
            float p3 = exp2f(sc[3][r]);
            lsum[r] += (p0 + p1) + (p2 + p3);
            int pr = quad * 4 + r;
            short* prow = &Ps[wave][pr * 64];
            int pm = pr & 7;
            int ch = l16 >> 3, kl = l16 & 7;
            prow[((ch ^ pm) << 3) + kl]       = f2s(p0);  // key l16       (chunk ch)
            prow[(((ch + 2) ^ pm) << 3) + kl] = f2s(p1);  // key 16+l16
            prow[(((ch + 4) ^ pm) << 3) + kl] = f2s(p2);  // key 32+l16
            prow[(((ch + 6) ^ pm) << 3) + kl] = f2s(p3);  // key 48+l16
        }

        // PV: O[16q x 64d] += P[16x64] * V[64x64]
        const short* prd = &Ps[wave][l16 * 64];
        short8 pa0 = *(const short8*)&prd[(quad ^ swz_m) * 8];
        short8 pa1 = *(const short8*)&prd[((quad + 4) ^ swz_m) * 8];
        #pragma unroll
        for (int nt = 0; nt < 4; ++nt) {
            const short* vr = &Vb[cur][(nt * 16 + l16) * 64];
            short8 bv0 = *(const short8*)&vr[(quad ^ swz_m) * 8];
            short8 bv1 = *(const short8*)&vr[((quad + 4) ^ swz_m) * 8];
            accO[nt] = __builtin_amdgcn_mfma_f32_16x16x32_bf16(pa0, bv0, accO[nt], 0, 0, 0);
            accO[nt] = __builtin_amdgcn_mfma_f32_16x16x32_bf16(pa1, bv1, accO[nt], 0, 0, 0);
        }

#if USE_GLL
        __builtin_amdgcn_s_barrier();   // all reads of buf[cur] done
#else
        __syncthreads();
#endif
        cur ^= 1;
    }

    #pragma unroll
    for (int r = 0; r < 4; ++r) {
        #pragma unroll
        for (int off = 1; off < 16; off <<= 1) lsum[r] += __shfl_xor(lsum[r], off);
    }

    size_t rowbase = ((size_t)split * 32 + bh) * NQ + q0;
    #pragma unroll
    for (int r = 0; r < 4; ++r) {
        size_t row = rowbase + quad * 4 + r;
        if (l16 == 0) pl[row] = lsum[r];
        #pragma unroll
        for (int nt = 0; nt < 4; ++nt)
            pacc[row * 64 + nt * 16 + l16] = accO[nt][r];
    }
}

// combine SPLIT partials -> bf16 attn output in (q, b, c) layout, x4 vectorized
__global__ __launch_bounds__(256) void attn_comb_k(const float* __restrict__ pl,
                                                   const float* __restrict__ pacc,
                                                   bf16* __restrict__ o) {
    int idx = blockIdx.x * 256 + threadIdx.x;   // 512K total (x4 elems)
    int d4 = (idx & 15) << 2;
    int row = idx >> 4;            // bh*NQ + q
    int q = row & (NQ - 1);
    int bh = row >> 10;
    const int S = 32 * NQ;
    float rl = 1.0f / (pl[row] + pl[S + row]);
    f32x4 a = *(const f32x4*)&pacc[(size_t)row * 64 + d4];
    f32x4 b = *(const f32x4*)&pacc[(size_t)(S + row) * 64 + d4];
    int bsel = bh >> 3, h = bh & 7;
    s16x4 o4;
    #pragma unroll
    for (int j = 0; j < 4; ++j) o4[j] = f2s((a[j] + b[j]) * rl);
    *(s16x4*)&o[((size_t)(q * BDIM + bsel)) * CDIM + h * HDQ + d4] = o4;
}

// ---------------- host side ----------------

extern "C" void kernel_launch(void* const* d_in, const int* in_sizes, int n_in,
                              void* d_out, int out_size, void* d_ws, size_t ws_size,
                              hipStream_t stream) {
    const float* query     = (const float*)d_in[0];
    const float* value     = (const float*)d_in[1];
    const float* diff_ts   = (const float*)d_in[2];
    const float* query_pos = (const float*)d_in[3];
    const float* value_pos = (const float*)d_in[4];
    const float* aw_attn   = (const float*)d_in[5];
    const float* ab_attn   = (const float*)d_in[6];
    const float* in_w      = (const float*)d_in[7];
    const float* in_b      = (const float*)d_in[8];
    const float* out_w     = (const float*)d_in[9];
    const float* out_b     = (const float*)d_in[10];
    const float* ln1_g     = (const float*)d_in[11];
    const float* ln1_b     = (const float*)d_in[12];
    const float* aw_ffn    = (const float*)d_in[13];
    const float* ab_ffn    = (const float*)d_in[14];
    const float* w1        = (const float*)d_in[15];
    const float* b1        = (const float*)d_in[16];
    const float* w2        = (const float*)d_in[17];
    const float* b2        = (const float*)d_in[18];
    const float* ln2_g     = (const float*)d_in[19];
    const float* ln2_b     = (const float*)d_in[20];
    float* out_f = (float*)d_out;

    float* ws      = (float*)d_ws;
    float* mod_ws  = ws + 2048;                 // 32768
    float* q_cur   = ws + 34816;                // 2,097,152
    float* buf_a   = q_cur + 2097152;           // 2,097,152 (xa f32 for LN2)
    float* buf_p   = buf_a + 2097152;           // 2,097,152 (proj f32 for LN res)
    bf16* a_bf     = (bf16*)(buf_p + 2097152);  // 2,097,152
    bf16* h_bf     = a_bf + 2097152;            // 2,097,152 (attn out / ffn hidden)
    bf16* qh       = h_bf + 2097152;            // 2,097,152
    bf16* kh       = qh + 2097152;              // 4,194,304
    bf16* vt       = kh + 4194304;              // 4,194,304 (V^T [bh][d][key])
    bf16* val_bf   = vt + 4194304;              // 4,194,304
    bf16* winb     = val_bf + 4194304;          // 3,145,728
    bf16* woutb    = winb + 3145728;            // 1,048,576
    bf16* w1b      = woutb + 1048576;           // 1,048,576
    bf16* w2b      = w1b + 1048576;             // 1,048,576
    // overlays (live only attn8 -> comb)
    float* pacc    = buf_a;                     // 4,194,304 f32 (buf_a..buf_p)
    float* pl      = (float*)a_bf;              // 131,072 f32 fits in a_bf

    const int MQ = NQ * BDIM;    // 4096
    // HD^-0.5 * log2(e): softmax then uses exp2 directly
    const float scaling = 0.125f * 1.44269504f;

    modall_k<<<8192, 256, 0, stream>>>(diff_ts, aw_attn, ab_attn, aw_ffn, ab_ffn, mod_ws);
    convall_k<<<10240, 256, 0, stream>>>(value, in_w, out_w, w1, w2,
                                         val_bf, winb, woutb, w1b, w2b);
    // aq for layer 0
    adaln_k<<<(MQ * CDIM) / 256, 256, 0, stream>>>(query, mod_ws, a_bf);

    for (int i = 0; i < LAYERS; ++i) {
        const float* mod_ffn  = mod_ws + i * 8192 + 4096;
        const float* mod_attn_next = (i + 1 < LAYERS) ? (mod_ws + (i + 1) * 8192) : nullptr;
        const bf16* winb_i = winb + (size_t)i * 1536 * CDIM;
        const float* in_b_i = in_b + (size_t)i * 1536;
        const float* qsrc = (i == 0) ? query : q_cur;

        // merged q/k/vT projections (one 768-block dispatch) -> qh, kh, vt
        qkv8_k<<<768, 512, 0, stream>>>(a_bf, val_bf, winb_i, in_b_i,
                                        qh, kh, vt, query_pos, value_pos, scaling);
        // attention: 8-wave staged blocks, then combine -> h_bf
        attn8_k<<<512, 512, 0, stream>>>(qh, kh, vt, pl, pacc);
        attn_comb_k<<<2048, 256, 0, stream>>>(pl, pacc, h_bf);
        // out proj -> buf_p f32
        mgemm_k<0, 2, 2, true><<<dim3(8, MQ / 64), 256, 0, stream>>>(
            h_bf, woutb + (size_t)i * CDIM * CDIM, out_b + i * CDIM, buf_p,
            MQ, 512, CDIM, nullptr, 0.f, 0);
        // q' = LN1(q + o); xa = adaln_ffn(q') -> buf_a f32 + a_bf bf16
        ln_ad_k<<<MQ, 256, 0, stream>>>(qsrc, buf_p,
                                        ln1_g + i * CDIM, ln1_b + i * CDIM,
                                        mod_ffn, nullptr, nullptr, buf_a, a_bf);
        // ffn1 relu -> h_bf bf16
        mgemm_k<1, 2, 2, true><<<dim3(8, MQ / 64), 256, 0, stream>>>(
            a_bf, w1b + (size_t)i * CDIM * CDIM, b1 + i * CDIM, h_bf,
            MQ, 512, CDIM, nullptr, 0.f, 0);
        // ffn2 -> buf_p f32
        mgemm_k<0, 2, 2, true><<<dim3(8, MQ / 64), 256, 0, stream>>>(
            h_bf, w2b + (size_t)i * CDIM * CDIM, b2 + i * CDIM, buf_p,
            MQ, 512, CDIM, nullptr, 0.f, 0);
        // q = LN2(xa + h) -> q_cur + out chunk; aq(next) = adaln_attn(q) -> a_bf
        ln_ad_k<<<MQ, 256, 0, stream>>>(buf_a, buf_p,
                                        ln2_g + i * CDIM, ln2_b + i * CDIM,
                                        mod_attn_next, q_cur,
                                        out_f + (size_t)i * MQ * CDIM, nullptr, a_bf);
    }
}